// Round 3
// baseline (2198.132 us; speedup 1.0000x reference)
//
#include <hip/hip_runtime.h>
#include <hip/hip_bf16.h>

// MapAgent: NatureCNN (3 convs + FC) -> map-write scan -> policy/value heads.
// T=32, B=64, TB=2048. All fp32.
//
// R3 changes (theory: conv2/conv3 were occupancy/TLP-starved — 64 oc/thread
// left 1.5 blocks/CU, Occupancy=18%, VALUBusy=27%; VGPR=44 showed the
// compiler strip-mined acc[64]):
//  * oc-group-per-wave: block = 64 spatial positions x 4 waves; wave w does
//    oc [16w,16w+16). oc0 wave-uniform -> weights stay on scalar path;
//    4x thread count, acc[16] in regs.
//  * channels-last activations [n][y][x][c]: all input taps and output
//    writes become contiguous float4s (image is NHWC natively; conv1 row
//    offsets are 16B aligned: 252*Y+12*ox floats).
//  * FC weight rows permuted (prep) to match conv3's [pos][c] k-order.

#define TT 32
#define BB 64
#define TBR 2048

// ---- common workspace offsets (floats) ----
#define OFF_W1T   0u          // 6144   : [ky][kx*3+c][32oc], pre-scaled /255
#define OFF_W2T   6144u       // 32768  : [tap16][c32][oc64]
#define OFF_W3T   38912u      // 36864  : [tap9][c64][oc64]
#define OFF_WFCP  75776u      // 1605632: wfc rows permuted (pos*64+c)
#define OFF_WF    1681408u    // 65536  : wfeat [2048][32]
#define OFF_PF    1746944u    // 131072 : posfeat [2048][64]
#define OFF_Y0    1878016u    // 8192   : y0 [64][128]
#define OFF_YS    1886208u    // 262144 : ystate [2048][128]
#define OFF_H     2148352u    // 1048576: h [2048][512]
#define OFF_END   3196928u    // conv buffers laid out per-tier after this

// ---------------- weight prep ----------------
__global__ __launch_bounds__(256) void prep_kernel(
    const float* __restrict__ w1, const float* __restrict__ w2,
    const float* __restrict__ w3, float* __restrict__ w1t,
    float* __restrict__ w2t, float* __restrict__ w3t) {
  int g = blockIdx.x * 256 + threadIdx.x;   // 75776 total
  if (g < 6144) {
    // conv1 k ordering = ky*24 + kx*3 + c ; w1 is [oc][c][ky*8+kx]
    int k = g >> 5, oc = g & 31;
    int c = k % 3, kyx = k / 3;
    w1t[g] = w1[oc * 192 + c * 64 + kyx] * (1.0f / 255.0f);
    return;
  }
  int g2 = g - 6144;
  if (g2 < 32768) {                          // w2t[(tap*32+c)*64+oc]
    int oc = g2 & 63, idx = g2 >> 6;
    int tap = idx >> 5, c = idx & 31;
    w2t[g2] = w2[oc * 512 + c * 16 + tap];
    return;
  }
  int g3 = g2 - 32768;
  if (g3 < 36864) {                          // w3t[(tap*64+c)*64+oc]
    int oc = g3 & 63, idx = g3 >> 6;
    int tap = idx >> 6, c = idx & 63;
    w3t[g3] = w3[oc * 576 + c * 9 + tap];
  }
}

// wfcp[(pos*64+c)*512+j] = wfc[(c*49+pos)*512+j]
__global__ __launch_bounds__(256) void prep_wfc(
    const float* __restrict__ wfc, float* __restrict__ wfcp) {
  int g = blockIdx.x * 256 + threadIdx.x;   // 1605632
  int j = g & 511, kk = g >> 9;
  int pos = kk >> 6, c = kk & 63;
  wfcp[g] = wfc[(size_t)(c * 49 + pos) * 512 + j];
}

// ---------------- conv1: NHWC 84x84x3 -> [20][20][32], 8x8 s4 ----------------
__global__ __launch_bounds__(256) void conv1_kernel(
    const float* __restrict__ img, const float* __restrict__ w1t,
    const float* __restrict__ b1, float* __restrict__ out, int n0) {
  int gid = blockIdx.x * 256 + threadIdx.x;  // CS*400
  int li = gid / 400;
  int pos = gid - li * 400;
  int oy = pos / 20, ox = pos - (pos / 20) * 20;
  float acc[32];
#pragma unroll
  for (int oc = 0; oc < 32; ++oc) acc[oc] = 0.f;
  const float* ib = img + (size_t)(n0 + li) * 21168;
  for (int ky = 0; ky < 8; ++ky) {
    // float offset = 252*(4oy+ky) + 12*ox : multiple of 4 -> 16B aligned
    const float4* rp = (const float4*)(ib + ((4 * oy + ky) * 84 + 4 * ox) * 3);
    float4 r[6];
#pragma unroll
    for (int q = 0; q < 6; ++q) r[q] = rp[q];
    const float* v = (const float*)r;        // 24 floats: kx*3+c
    const float* wk = w1t + ky * 24 * 32;
#pragma unroll
    for (int i = 0; i < 24; ++i) {
      float vv = v[i];
      const float* wr = wk + i * 32;         // wave-uniform -> s_load
#pragma unroll
      for (int oc = 0; oc < 32; ++oc) acc[oc] += vv * wr[oc];
    }
  }
  float4* ob = (float4*)(out + (size_t)li * 12800 + pos * 32);
#pragma unroll
  for (int q = 0; q < 8; ++q) {
    float4 o;
    o.x = fmaxf(acc[4 * q] + b1[4 * q], 0.f);
    o.y = fmaxf(acc[4 * q + 1] + b1[4 * q + 1], 0.f);
    o.z = fmaxf(acc[4 * q + 2] + b1[4 * q + 2], 0.f);
    o.w = fmaxf(acc[4 * q + 3] + b1[4 * q + 3], 0.f);
    ob[q] = o;
  }
}

// ---------------- conv2: [20][20][32] -> [9][9][64], 4x4 s2 ----------------
// Block = 64 positions x 4 waves; wave w -> oc [16w,16w+16).
__global__ __launch_bounds__(256) void conv2_kernel(
    const float* __restrict__ in, const float* __restrict__ w2t,
    const float* __restrict__ b2, float* __restrict__ out) {
  int lane = threadIdx.x & 63;
  int oc0 = (threadIdx.x >> 6) * 16;         // wave-uniform
  int p = blockIdx.x * 64 + lane;            // CS*81 exact
  int li = p / 81;
  int pos = p - li * 81;
  int oy = pos / 9, ox = pos - (pos / 9) * 9;
  float acc[16];
#pragma unroll
  for (int j = 0; j < 16; ++j) acc[j] = 0.f;
  const float* ib = in + (size_t)li * 12800;
#pragma unroll
  for (int ky = 0; ky < 4; ++ky) {
#pragma unroll
    for (int kx = 0; kx < 4; ++kx) {
      const float* ip = ib + ((2 * oy + ky) * 20 + (2 * ox + kx)) * 32;
      const float* wk = w2t + (size_t)((ky * 4 + kx) * 32) * 64 + oc0;
#pragma unroll
      for (int cc = 0; cc < 32; cc += 16) {
        float4 a[4];
        const float4* ip4 = (const float4*)(ip + cc);
#pragma unroll
        for (int q = 0; q < 4; ++q) a[q] = ip4[q];
        const float* v = (const float*)a;
#pragma unroll
        for (int c = 0; c < 16; ++c) {
          float vv = v[c];
          const float* wr = wk + (cc + c) * 64;  // wave-uniform
#pragma unroll
          for (int j = 0; j < 16; ++j) acc[j] += vv * wr[j];
        }
      }
    }
  }
  float4* ob = (float4*)(out + (size_t)li * 5184 + pos * 64 + oc0);
#pragma unroll
  for (int q = 0; q < 4; ++q) {
    float4 o;
    o.x = fmaxf(acc[4 * q] + b2[oc0 + 4 * q], 0.f);
    o.y = fmaxf(acc[4 * q + 1] + b2[oc0 + 4 * q + 1], 0.f);
    o.z = fmaxf(acc[4 * q + 2] + b2[oc0 + 4 * q + 2], 0.f);
    o.w = fmaxf(acc[4 * q + 3] + b2[oc0 + 4 * q + 3], 0.f);
    ob[q] = o;
  }
}

// ---------------- conv3: [9][9][64] -> [49][64], 3x3 s1 ----------------
// Output row layout per image: pos*64 + c (FC uses permuted wfc).
__global__ __launch_bounds__(256) void conv3_kernel(
    const float* __restrict__ in, const float* __restrict__ w3t,
    const float* __restrict__ b3, float* __restrict__ out) {
  int lane = threadIdx.x & 63;
  int oc0 = (threadIdx.x >> 6) * 16;         // wave-uniform
  int p = blockIdx.x * 64 + lane;            // count*49 exact
  int li = p / 49;
  int pos = p - li * 49;
  int oy = pos / 7, ox = pos - (pos / 7) * 7;
  float acc[16];
#pragma unroll
  for (int j = 0; j < 16; ++j) acc[j] = 0.f;
  const float* ib = in + (size_t)li * 5184;
#pragma unroll
  for (int ky = 0; ky < 3; ++ky) {
#pragma unroll
    for (int kx = 0; kx < 3; ++kx) {
      const float* ip = ib + ((oy + ky) * 9 + ox + kx) * 64;
      const float* wk = w3t + (size_t)((ky * 3 + kx) * 64) * 64 + oc0;
#pragma unroll
      for (int cc = 0; cc < 64; cc += 16) {
        float4 a[4];
        const float4* ip4 = (const float4*)(ip + cc);
#pragma unroll
        for (int q = 0; q < 4; ++q) a[q] = ip4[q];
        const float* v = (const float*)a;
#pragma unroll
        for (int c = 0; c < 16; ++c) {
          float vv = v[c];
          const float* wr = wk + (cc + c) * 64;  // wave-uniform
#pragma unroll
          for (int j = 0; j < 16; ++j) acc[j] += vv * wr[j];
        }
      }
    }
  }
  float4* ob = (float4*)(out + (size_t)li * 3136 + pos * 64 + oc0);
#pragma unroll
  for (int q = 0; q < 4; ++q) {
    float4 o;
    o.x = fmaxf(acc[4 * q] + b3[oc0 + 4 * q], 0.f);
    o.y = fmaxf(acc[4 * q + 1] + b3[oc0 + 4 * q + 1], 0.f);
    o.z = fmaxf(acc[4 * q + 2] + b3[oc0 + 4 * q + 2], 0.f);
    o.w = fmaxf(acc[4 * q + 3] + b3[oc0 + 4 * q + 3], 0.f);
    ob[q] = o;
  }
}

// ---------------- FC: [2048,3136] @ [3136,512] + bias, ReLU ----------------
// LDS-tiled fp32 GEMM: BM=64, BN=64, BK=16, 256 threads, thread tile 4x4.
__global__ __launch_bounds__(256) void fc_gemm(
    const float* __restrict__ A, const float* __restrict__ Bw,
    const float* __restrict__ bias, float* __restrict__ C) {
  __shared__ float As[16][68];
  __shared__ float Bs[16][68];
  int tid = threadIdx.x;
  int m0 = blockIdx.y * 64, n0 = blockIdx.x * 64;
  int tx = tid & 15, ty = tid >> 4;
  int aRow = tid & 63;
  int aK = (tid >> 6) * 4;
  int bN = tid & 63;
  int bK = tid >> 6;
  float acc[4][4];
#pragma unroll
  for (int i = 0; i < 4; ++i)
#pragma unroll
    for (int j = 0; j < 4; ++j) acc[i][j] = 0.f;
  const float* aBase = A + (size_t)(m0 + aRow) * 3136;
  for (int k0 = 0; k0 < 3136; k0 += 16) {
    float4 av = *(const float4*)(aBase + k0 + aK);
    float bv[4];
#pragma unroll
    for (int j = 0; j < 4; ++j)
      bv[j] = Bw[(size_t)(k0 + bK + 4 * j) * 512 + n0 + bN];
    __syncthreads();
#pragma unroll
    for (int j = 0; j < 4; ++j) Bs[bK + 4 * j][bN] = bv[j];
    As[aK][aRow] = av.x;
    As[aK + 1][aRow] = av.y;
    As[aK + 2][aRow] = av.z;
    As[aK + 3][aRow] = av.w;
    __syncthreads();
#pragma unroll
    for (int kk = 0; kk < 16; ++kk) {
      float4 a = *(const float4*)&As[kk][ty * 4];
      float4 b = *(const float4*)&Bs[kk][tx * 4];
      float af[4] = {a.x, a.y, a.z, a.w};
      float bf[4] = {b.x, b.y, b.z, b.w};
#pragma unroll
      for (int i = 0; i < 4; ++i)
#pragma unroll
        for (int j = 0; j < 4; ++j) acc[i][j] += af[i] * bf[j];
    }
  }
#pragma unroll
  for (int i = 0; i < 4; ++i) {
#pragma unroll
    for (int j = 0; j < 4; ++j) {
      int m = m0 + ty * 4 + i, n = n0 + tx * 4 + j;
      C[(size_t)m * 512 + n] = fmaxf(acc[i][j] + bias[n], 0.f);
    }
  }
}

// ---------------- wfeat = h @ Ww + bw : [2048,512]@[512,32] ----------------
__global__ __launch_bounds__(256) void wfeat_kernel(
    const float* __restrict__ h, const float* __restrict__ Ww,
    const float* __restrict__ bw, float* __restrict__ wf) {
  int g = blockIdx.x * 256 + threadIdx.x;   // 65536
  int row = g >> 5, oc = g & 31;
  float acc = bw[oc];
  const float* hr = h + (size_t)row * 512;
#pragma unroll 8
  for (int k = 0; k < 512; ++k) acc += hr[k] * Ww[k * 32 + oc];
  wf[g] = acc;
}

// ---------------- posfeat: one-hot MLP, one wave per row ----------------
__global__ __launch_bounds__(256) void posfeat_kernel(
    const int* __restrict__ pos, const float* __restrict__ wp1,
    const float* __restrict__ bp1, const float* __restrict__ wp2,
    const float* __restrict__ bp2, float* __restrict__ pf) {
  int row = (blockIdx.x * 256 + threadIdx.x) >> 6;  // 2048
  int l = threadIdx.x & 63;
  int p0 = pos[row * 2], p1 = pos[row * 2 + 1];
  float t1 = fmaxf(wp1[p0 * 64 + l] + wp1[(16 + p1) * 64 + l] + bp1[l], 0.f);
  float acc = bp2[l];
#pragma unroll
  for (int k = 0; k < 64; ++k) acc += __shfl(t1, k) * wp2[k * 64 + l];
  pf[row * 64 + l] = acc;
}

// ---------------- y0 = state0 @ [wpo1|wv1] : [64,8192]@[8192,128] ----------------
__global__ __launch_bounds__(256) void y0_kernel(
    const float* __restrict__ s0, const float* __restrict__ wpo1,
    const float* __restrict__ wv1, float* __restrict__ y0) {
  int g = blockIdx.x * 256 + threadIdx.x;   // 65536: (b, ks, n)
  int n = g & 127, ks = (g >> 7) & 7, b = g >> 10;
  const float* W = (n < 64) ? (wpo1 + n) : (wv1 + (n - 64));
  const float* s = s0 + (size_t)b * 8192 + ks * 1024;
  float acc = 0.f;
#pragma unroll 4
  for (int j = 0; j < 1024; ++j) acc += s[j] * W[(size_t)(ks * 1024 + j) * 64];
  atomicAdd(y0 + b * 128 + n, acc);
}

// ---------------- ystate: recurrence for hidden@W1 (cols 0..8191) ----------------
__global__ __launch_bounds__(128) void ystate_kernel(
    const float* __restrict__ y0, const float* __restrict__ done,
    const int* __restrict__ pos, const float* __restrict__ wf,
    const float* __restrict__ wpo1, const float* __restrict__ wv1,
    float* __restrict__ ys) {
  int b = blockIdx.x;
  int n = threadIdx.x;                      // 0..127
  const float* W = (n < 64) ? (wpo1 + n) : (wv1 + (n - 64));
  float y = y0[b * 128 + n];
  for (int t = 0; t < TT; ++t) {
    int row = t * BB + b;
    float mask = 1.f - done[row];
    int off = pos[row * 2] * 16 + pos[row * 2 + 1];
    y *= mask;
    const float* wfr = wf + row * 32;
#pragma unroll
    for (int c = 0; c < 32; ++c) y += wfr[c] * W[(size_t)(c * 256 + off) * 64];
    ys[(size_t)row * 128 + n] = y;
  }
}

// ---------------- final map state (output 2) ----------------
__global__ __launch_bounds__(256) void state_kernel(
    const float* __restrict__ s0, const float* __restrict__ done,
    const int* __restrict__ pos, const float* __restrict__ wf,
    float* __restrict__ out_state) {
  int b = blockIdx.x, tid = threadIdx.x;    // tid = spatial offset 0..255
  float s[32];
#pragma unroll
  for (int c = 0; c < 32; ++c) s[c] = s0[(size_t)b * 8192 + c * 256 + tid];
  for (int t = 0; t < TT; ++t) {
    int row = t * BB + b;
    float mask = 1.f - done[row];
    int off = pos[row * 2] * 16 + pos[row * 2 + 1];
#pragma unroll
    for (int c = 0; c < 32; ++c) s[c] *= mask;
    if (tid == off) {
#pragma unroll
      for (int c = 0; c < 32; ++c) s[c] += wf[row * 32 + c];
    }
  }
#pragma unroll
  for (int c = 0; c < 32; ++c) out_state[(size_t)b * 8192 + c * 256 + tid] = s[c];
}

// ---------------- heads: + pos-part of W1, ReLU, second layers ----------------
__global__ __launch_bounds__(256) void head_kernel(
    const float* __restrict__ ys, const float* __restrict__ pf,
    const float* __restrict__ wpo1, const float* __restrict__ wv1,
    const float* __restrict__ bpo1, const float* __restrict__ bv1,
    const float* __restrict__ wpo2, const float* __restrict__ bpo2,
    const float* __restrict__ wv2, const float* __restrict__ bv2,
    float* __restrict__ logits, float* __restrict__ vout) {
  int row = (blockIdx.x * 256 + threadIdx.x) >> 6;  // one wave per row
  int l = threadIdx.x & 63;
  float pfv = pf[row * 64 + l];
  float accp = bpo1[l] + ys[(size_t)row * 128 + l];
  float accv = bv1[l] + ys[(size_t)row * 128 + 64 + l];
#pragma unroll
  for (int k = 0; k < 64; ++k) {
    float pk = __shfl(pfv, k);
    accp += pk * wpo1[(size_t)(8192 + k) * 64 + l];
    accv += pk * wv1[(size_t)(8192 + k) * 64 + l];
  }
  float rp = fmaxf(accp, 0.f), rv = fmaxf(accv, 0.f);
#pragma unroll
  for (int a = 0; a < 5; ++a) {
    float pa = rp * wpo2[l * 5 + a];
#pragma unroll
    for (int m = 32; m >= 1; m >>= 1) pa += __shfl_xor(pa, m);
    if (l == 0) logits[row * 5 + a] = pa + bpo2[a];
  }
  float pv = rv * wv2[l];
#pragma unroll
  for (int m = 32; m >= 1; m >>= 1) pv += __shfl_xor(pv, m);
  if (l == 0) vout[row] = pv + bv2[0];
}

extern "C" void kernel_launch(void* const* d_in, const int* in_sizes, int n_in,
                              void* d_out, int out_size, void* d_ws, size_t ws_size,
                              hipStream_t stream) {
  const float* image = (const float*)d_in[0];
  const float* done = (const float*)d_in[1];
  const float* state0 = (const float*)d_in[2];
  const int* position = (const int*)d_in[3];
  const float* w1 = (const float*)d_in[4];
  const float* b1 = (const float*)d_in[5];
  const float* w2 = (const float*)d_in[6];
  const float* b2 = (const float*)d_in[7];
  const float* w3 = (const float*)d_in[8];
  const float* b3 = (const float*)d_in[9];
  const float* wfc = (const float*)d_in[10];
  const float* bfc = (const float*)d_in[11];
  const float* Ww = (const float*)d_in[12];
  const float* bw = (const float*)d_in[13];
  const float* wp1 = (const float*)d_in[14];
  const float* bp1 = (const float*)d_in[15];
  const float* wp2 = (const float*)d_in[16];
  const float* bp2 = (const float*)d_in[17];
  const float* wpo1 = (const float*)d_in[18];
  const float* bpo1 = (const float*)d_in[19];
  const float* wpo2 = (const float*)d_in[20];
  const float* bpo2 = (const float*)d_in[21];
  const float* wv1 = (const float*)d_in[22];
  const float* bv1 = (const float*)d_in[23];
  const float* wv2 = (const float*)d_in[24];
  const float* bv2 = (const float*)d_in[25];

  float* ws = (float*)d_ws;
  float* w1t = ws + OFF_W1T;
  float* w2t = ws + OFF_W2T;
  float* w3t = ws + OFF_W3T;
  float* wfcp = ws + OFF_WFCP;
  float* wf = ws + OFF_WF;
  float* pfb = ws + OFF_PF;
  float* y0 = ws + OFF_Y0;
  float* ysb = ws + OFF_YS;
  float* h = ws + OFF_H;

  float* out = (float*)d_out;
  float* out_logits = out;            // [2048,5]
  float* out_v = out + 10240;         // [2048,1]
  float* out_state = out + 12288;     // [64,32,16,16]

  // Tier selection by ws_size:
  //  tier1: CS=1024, full c2b, conv3 once.     needs 107.69 MB
  //  tier2: CS=512,  chunked c2b+conv3.        needs 75.31 MB
  //  tier3: CS=256,  chunked c2b+conv3.        needs 56.90 MB
  int tier, CS;
  if (ws_size >= (size_t)26920960 * 4) { tier = 1; CS = 1024; }
  else if (ws_size >= (size_t)18827264 * 4) { tier = 2; CS = 512; }
  else { tier = 3; CS = 256; }
  int nc = TBR / CS;

  float *c2b, *c1b, *c3b;
  if (tier == 1) {
    c2b = ws + OFF_END;                       // [2048][5184]
    c1b = ws + OFF_END + 10616832u;           // [1024][12800]
    c3b = c1b;                                // reuse after chunks done
  } else {
    c2b = ws + OFF_END;                       // [CS][5184]
    c1b = c2b + (size_t)CS * 5184;            // [CS][12800]
    c3b = c1b + (size_t)CS * 12800;           // [2048][3136]
  }

  hipMemsetAsync(y0, 0, 8192 * sizeof(float), stream);
  prep_kernel<<<296, 256, 0, stream>>>(w1, w2, w3, w1t, w2t, w3t);
  prep_wfc<<<6272, 256, 0, stream>>>(wfc, wfcp);

  for (int c = 0; c < nc; ++c) {
    int n0 = c * CS;
    conv1_kernel<<<CS * 400 / 256, 256, 0, stream>>>(image, w1t, b1, c1b, n0);
    float* c2dst = (tier == 1) ? (c2b + (size_t)n0 * 5184) : c2b;
    conv2_kernel<<<CS * 81 / 64, 256, 0, stream>>>(c1b, w2t, b2, c2dst);
    if (tier != 1) {
      conv3_kernel<<<CS * 49 / 64, 256, 0, stream>>>(
          c2b, w3t, b3, c3b + (size_t)n0 * 3136);
    }
  }
  if (tier == 1) {
    conv3_kernel<<<TBR * 49 / 64, 256, 0, stream>>>(c2b, w3t, b3, c3b);
  }
  fc_gemm<<<dim3(8, 32), 256, 0, stream>>>(c3b, wfcp, bfc, h);
  wfeat_kernel<<<256, 256, 0, stream>>>(h, Ww, bw, wf);
  posfeat_kernel<<<512, 256, 0, stream>>>(position, wp1, bp1, wp2, bp2, pfb);
  y0_kernel<<<256, 256, 0, stream>>>(state0, wpo1, wv1, y0);
  ystate_kernel<<<64, 128, 0, stream>>>(y0, done, position, wf, wpo1, wv1, ysb);
  state_kernel<<<64, 256, 0, stream>>>(state0, done, position, wf, out_state);
  head_kernel<<<512, 256, 0, stream>>>(ysb, pfb, wpo1, wv1, bpo1, bv1,
                                       wpo2, bpo2, wv2, bv2, out_logits, out_v);
}

// Round 4
// 1129.882 us; speedup vs baseline: 1.9455x; 1.9455x over previous
//
#include <hip/hip_runtime.h>
#include <hip/hip_bf16.h>

// MapAgent: NatureCNN (3 convs + FC) -> map-write scan -> policy/value heads.
// T=32, B=64, TB=2048. All fp32.
//
// R4 changes (theory: R3 regressed because oc0 derived from threadIdx.x is
// not PROVABLY uniform -> weights fell off the scalar path; SGPR_Count
// dropped 112->32, VALUBusy 10%):
//  * oc-split moved to blockIdx.y (SGPR by construction) -> weights are
//    guaranteed s_load. Block = 256 spatial positions, grid.y = oc groups
//    of 16. acc[16] fits registers; 4x TLP vs R2.
//  * activations back to NCHW (R2 layout): lane = consecutive spatial pos
//    -> all input loads / output stores fully coalesced scalar accesses
//    (R3's NHWC scattered each wave access over ~64 cache lines).
//  * conv3 out k-order = c*49+pos = original wfc order -> prep_wfc dropped.

#define TT 32
#define BB 64
#define TBR 2048

// ---- workspace offsets (floats) ----
#define OFF_W1T   0u          // 6144   : [ky][kx*3+c][32oc], pre-scaled /255
#define OFF_W2T   6144u       // 32768  : [c*16+tap][oc64]
#define OFF_W3T   38912u      // 36864  : [c*9+tap][oc64]
#define OFF_WF    75776u      // 65536  : wfeat [2048][32]
#define OFF_PF    141312u     // 131072 : posfeat [2048][64]
#define OFF_Y0    272384u     // 8192   : y0 [64][128]
#define OFF_YS    280576u     // 262144 : ystate [2048][128]
#define OFF_H     542720u     // 1048576: h [2048][512]
#define OFF_END   1591296u    // conv buffers laid out per-tier after this

// ---------------- weight prep ----------------
__global__ __launch_bounds__(256) void prep_kernel(
    const float* __restrict__ w1, const float* __restrict__ w2,
    const float* __restrict__ w3, float* __restrict__ w1t,
    float* __restrict__ w2t, float* __restrict__ w3t) {
  int g = blockIdx.x * 256 + threadIdx.x;   // 75776 total
  if (g < 6144) {
    // conv1 k ordering = ky*24 + kx*3 + c ; w1 is [oc][c][ky*8+kx]
    int k = g >> 5, oc = g & 31;
    int c = k % 3, kyx = k / 3;
    w1t[g] = w1[oc * 192 + c * 64 + kyx] * (1.0f / 255.0f);
    return;
  }
  int g2 = g - 6144;
  if (g2 < 32768) {                          // w2t[(c*16+tap)*64+oc]
    int k = g2 >> 6, oc = g2 & 63;           // k = c*16+tap matches w2 [oc][c][tap]
    w2t[g2] = w2[oc * 512 + k];
    return;
  }
  int g3 = g2 - 32768;
  if (g3 < 36864) {                          // w3t[(c*9+tap)*64+oc]
    int k = g3 >> 6, oc = g3 & 63;
    w3t[g3] = w3[oc * 576 + k];
  }
}

// ---------------- conv1: NHWC 84x84x3 -> NCHW [32][20][20], 8x8 s4 ----------
// grid = (CS*400/256, 2); blockIdx.y picks oc group of 16 (SGPR-uniform).
__global__ __launch_bounds__(256) void conv1_kernel(
    const float* __restrict__ img, const float* __restrict__ w1t,
    const float* __restrict__ b1, float* __restrict__ out, int n0) {
  int gid = blockIdx.x * 256 + threadIdx.x;  // CS*400
  int oc0 = blockIdx.y * 16;                 // SGPR
  int li = gid / 400;
  int pos = gid - li * 400;
  int oy = pos / 20, ox = pos - (pos / 20) * 20;
  float acc[16];
#pragma unroll
  for (int j = 0; j < 16; ++j) acc[j] = 0.f;
  const float* ib = img + (size_t)(n0 + li) * 21168;
  for (int ky = 0; ky < 8; ++ky) {
    // float offset = 252*(4oy+ky) + 12*ox : multiple of 4 -> 16B aligned
    const float4* rp = (const float4*)(ib + ((4 * oy + ky) * 84 + 4 * ox) * 3);
    float4 r[6];
#pragma unroll
    for (int q = 0; q < 6; ++q) r[q] = rp[q];
    const float* v = (const float*)r;        // 24 floats: kx*3+c
    const float* wk = w1t + ky * 24 * 32 + oc0;
#pragma unroll
    for (int i = 0; i < 24; ++i) {
      float vv = v[i];
      const float* wr = wk + i * 32;         // uniform -> s_load
#pragma unroll
      for (int j = 0; j < 16; ++j) acc[j] += vv * wr[j];
    }
  }
  float* ob = out + (size_t)li * 12800 + pos;
#pragma unroll
  for (int j = 0; j < 16; ++j)
    ob[(oc0 + j) * 400] = fmaxf(acc[j] + b1[oc0 + j], 0.f);  // coalesced
}

// ---------------- conv2: NCHW [32][20][20] -> [64][9][9], 4x4 s2 ------------
// grid = (CS*81/256, 4); blockIdx.y picks oc group of 16.
__global__ __launch_bounds__(256) void conv2_kernel(
    const float* __restrict__ in, const float* __restrict__ w2t,
    const float* __restrict__ b2, float* __restrict__ out) {
  int p = blockIdx.x * 256 + threadIdx.x;    // CS*81
  int oc0 = blockIdx.y * 16;                 // SGPR
  int li = p / 81;
  int pos = p - li * 81;
  int oy = pos / 9, ox = pos - (pos / 9) * 9;
  float acc[16];
#pragma unroll
  for (int j = 0; j < 16; ++j) acc[j] = 0.f;
  const float* ib = in + (size_t)li * 12800;
  for (int c = 0; c < 32; ++c) {
#pragma unroll
    for (int ky = 0; ky < 4; ++ky) {
      const float* row = ib + (c * 20 + 2 * oy + ky) * 20 + 2 * ox;
      const float* wk = w2t + (c * 16 + ky * 4) * 64 + oc0;
#pragma unroll
      for (int kx = 0; kx < 4; ++kx) {
        float vv = row[kx];                  // lane-coalesced (stride 2)
        const float* wr = wk + kx * 64;      // uniform -> s_load
#pragma unroll
        for (int j = 0; j < 16; ++j) acc[j] += vv * wr[j];
      }
    }
  }
  float* ob = out + (size_t)li * 5184 + pos;
#pragma unroll
  for (int j = 0; j < 16; ++j)
    ob[(oc0 + j) * 81] = fmaxf(acc[j] + b2[oc0 + j], 0.f);   // coalesced
}

// ---------------- conv3: NCHW [64][9][9] -> [64][7][7], 3x3 s1 --------------
// grid = (count*49/256, 4). Output rows [c*49+pos] = original wfc k-order.
__global__ __launch_bounds__(256) void conv3_kernel(
    const float* __restrict__ in, const float* __restrict__ w3t,
    const float* __restrict__ b3, float* __restrict__ out) {
  int p = blockIdx.x * 256 + threadIdx.x;    // count*49
  int oc0 = blockIdx.y * 16;                 // SGPR
  int li = p / 49;
  int pos = p - li * 49;
  int oy = pos / 7, ox = pos - (pos / 7) * 7;
  float acc[16];
#pragma unroll
  for (int j = 0; j < 16; ++j) acc[j] = 0.f;
  const float* ib = in + (size_t)li * 5184;
  for (int c = 0; c < 64; ++c) {
    const float* rb = ib + (c * 9 + oy) * 9 + ox;
    float v[9];
#pragma unroll
    for (int ky = 0; ky < 3; ++ky) {
#pragma unroll
      for (int kx = 0; kx < 3; ++kx) v[ky * 3 + kx] = rb[ky * 9 + kx];
    }
    const float* wk = w3t + c * 9 * 64 + oc0;
#pragma unroll
    for (int t = 0; t < 9; ++t) {
      float vv = v[t];
      const float* wr = wk + t * 64;         // uniform -> s_load
#pragma unroll
      for (int j = 0; j < 16; ++j) acc[j] += vv * wr[j];
    }
  }
  float* ob = out + (size_t)li * 3136 + pos;
#pragma unroll
  for (int j = 0; j < 16; ++j)
    ob[(oc0 + j) * 49] = fmaxf(acc[j] + b3[oc0 + j], 0.f);   // coalesced
}

// ---------------- FC: [2048,3136] @ [3136,512] + bias, ReLU ----------------
// LDS-tiled fp32 GEMM: BM=64, BN=64, BK=16, 256 threads, thread tile 4x4.
__global__ __launch_bounds__(256) void fc_gemm(
    const float* __restrict__ A, const float* __restrict__ Bw,
    const float* __restrict__ bias, float* __restrict__ C) {
  __shared__ float As[16][68];
  __shared__ float Bs[16][68];
  int tid = threadIdx.x;
  int m0 = blockIdx.y * 64, n0 = blockIdx.x * 64;
  int tx = tid & 15, ty = tid >> 4;
  int aRow = tid & 63;
  int aK = (tid >> 6) * 4;
  int bN = tid & 63;
  int bK = tid >> 6;
  float acc[4][4];
#pragma unroll
  for (int i = 0; i < 4; ++i)
#pragma unroll
    for (int j = 0; j < 4; ++j) acc[i][j] = 0.f;
  const float* aBase = A + (size_t)(m0 + aRow) * 3136;
  for (int k0 = 0; k0 < 3136; k0 += 16) {
    float4 av = *(const float4*)(aBase + k0 + aK);
    float bv[4];
#pragma unroll
    for (int j = 0; j < 4; ++j)
      bv[j] = Bw[(size_t)(k0 + bK + 4 * j) * 512 + n0 + bN];
    __syncthreads();
#pragma unroll
    for (int j = 0; j < 4; ++j) Bs[bK + 4 * j][bN] = bv[j];
    As[aK][aRow] = av.x;
    As[aK + 1][aRow] = av.y;
    As[aK + 2][aRow] = av.z;
    As[aK + 3][aRow] = av.w;
    __syncthreads();
#pragma unroll
    for (int kk = 0; kk < 16; ++kk) {
      float4 a = *(const float4*)&As[kk][ty * 4];
      float4 b = *(const float4*)&Bs[kk][tx * 4];
      float af[4] = {a.x, a.y, a.z, a.w};
      float bf[4] = {b.x, b.y, b.z, b.w};
#pragma unroll
      for (int i = 0; i < 4; ++i)
#pragma unroll
        for (int j = 0; j < 4; ++j) acc[i][j] += af[i] * bf[j];
    }
  }
#pragma unroll
  for (int i = 0; i < 4; ++i) {
#pragma unroll
    for (int j = 0; j < 4; ++j) {
      int m = m0 + ty * 4 + i, n = n0 + tx * 4 + j;
      C[(size_t)m * 512 + n] = fmaxf(acc[i][j] + bias[n], 0.f);
    }
  }
}

// ---------------- wfeat = h @ Ww + bw : [2048,512]@[512,32] ----------------
__global__ __launch_bounds__(256) void wfeat_kernel(
    const float* __restrict__ h, const float* __restrict__ Ww,
    const float* __restrict__ bw, float* __restrict__ wf) {
  int g = blockIdx.x * 256 + threadIdx.x;   // 65536
  int row = g >> 5, oc = g & 31;
  float acc = bw[oc];
  const float* hr = h + (size_t)row * 512;
#pragma unroll 8
  for (int k = 0; k < 512; ++k) acc += hr[k] * Ww[k * 32 + oc];
  wf[g] = acc;
}

// ---------------- posfeat: one-hot MLP, one wave per row ----------------
__global__ __launch_bounds__(256) void posfeat_kernel(
    const int* __restrict__ pos, const float* __restrict__ wp1,
    const float* __restrict__ bp1, const float* __restrict__ wp2,
    const float* __restrict__ bp2, float* __restrict__ pf) {
  int row = (blockIdx.x * 256 + threadIdx.x) >> 6;  // 2048
  int l = threadIdx.x & 63;
  int p0 = pos[row * 2], p1 = pos[row * 2 + 1];
  float t1 = fmaxf(wp1[p0 * 64 + l] + wp1[(16 + p1) * 64 + l] + bp1[l], 0.f);
  float acc = bp2[l];
#pragma unroll
  for (int k = 0; k < 64; ++k) acc += __shfl(t1, k) * wp2[k * 64 + l];
  pf[row * 64 + l] = acc;
}

// ---------------- y0 = state0 @ [wpo1|wv1] : [64,8192]@[8192,128] ----------------
__global__ __launch_bounds__(256) void y0_kernel(
    const float* __restrict__ s0, const float* __restrict__ wpo1,
    const float* __restrict__ wv1, float* __restrict__ y0) {
  int g = blockIdx.x * 256 + threadIdx.x;   // 65536: (b, ks, n)
  int n = g & 127, ks = (g >> 7) & 7, b = g >> 10;
  const float* W = (n < 64) ? (wpo1 + n) : (wv1 + (n - 64));
  const float* s = s0 + (size_t)b * 8192 + ks * 1024;
  float acc = 0.f;
#pragma unroll 4
  for (int j = 0; j < 1024; ++j) acc += s[j] * W[(size_t)(ks * 1024 + j) * 64];
  atomicAdd(y0 + b * 128 + n, acc);
}

// ---------------- ystate: recurrence for hidden@W1 (cols 0..8191) ----------------
__global__ __launch_bounds__(128) void ystate_kernel(
    const float* __restrict__ y0, const float* __restrict__ done,
    const int* __restrict__ pos, const float* __restrict__ wf,
    const float* __restrict__ wpo1, const float* __restrict__ wv1,
    float* __restrict__ ys) {
  int b = blockIdx.x;
  int n = threadIdx.x;                      // 0..127
  const float* W = (n < 64) ? (wpo1 + n) : (wv1 + (n - 64));
  float y = y0[b * 128 + n];
  for (int t = 0; t < TT; ++t) {
    int row = t * BB + b;
    float mask = 1.f - done[row];
    int off = pos[row * 2] * 16 + pos[row * 2 + 1];
    y *= mask;
    const float* wfr = wf + row * 32;
#pragma unroll
    for (int c = 0; c < 32; ++c) y += wfr[c] * W[(size_t)(c * 256 + off) * 64];
    ys[(size_t)row * 128 + n] = y;
  }
}

// ---------------- final map state (output 2) ----------------
__global__ __launch_bounds__(256) void state_kernel(
    const float* __restrict__ s0, const float* __restrict__ done,
    const int* __restrict__ pos, const float* __restrict__ wf,
    float* __restrict__ out_state) {
  int b = blockIdx.x, tid = threadIdx.x;    // tid = spatial offset 0..255
  float s[32];
#pragma unroll
  for (int c = 0; c < 32; ++c) s[c] = s0[(size_t)b * 8192 + c * 256 + tid];
  for (int t = 0; t < TT; ++t) {
    int row = t * BB + b;
    float mask = 1.f - done[row];
    int off = pos[row * 2] * 16 + pos[row * 2 + 1];
#pragma unroll
    for (int c = 0; c < 32; ++c) s[c] *= mask;
    if (tid == off) {
#pragma unroll
      for (int c = 0; c < 32; ++c) s[c] += wf[row * 32 + c];
    }
  }
#pragma unroll
  for (int c = 0; c < 32; ++c) out_state[(size_t)b * 8192 + c * 256 + tid] = s[c];
}

// ---------------- heads: + pos-part of W1, ReLU, second layers ----------------
__global__ __launch_bounds__(256) void head_kernel(
    const float* __restrict__ ys, const float* __restrict__ pf,
    const float* __restrict__ wpo1, const float* __restrict__ wv1,
    const float* __restrict__ bpo1, const float* __restrict__ bv1,
    const float* __restrict__ wpo2, const float* __restrict__ bpo2,
    const float* __restrict__ wv2, const float* __restrict__ bv2,
    float* __restrict__ logits, float* __restrict__ vout) {
  int row = (blockIdx.x * 256 + threadIdx.x) >> 6;  // one wave per row
  int l = threadIdx.x & 63;
  float pfv = pf[row * 64 + l];
  float accp = bpo1[l] + ys[(size_t)row * 128 + l];
  float accv = bv1[l] + ys[(size_t)row * 128 + 64 + l];
#pragma unroll
  for (int k = 0; k < 64; ++k) {
    float pk = __shfl(pfv, k);
    accp += pk * wpo1[(size_t)(8192 + k) * 64 + l];
    accv += pk * wv1[(size_t)(8192 + k) * 64 + l];
  }
  float rp = fmaxf(accp, 0.f), rv = fmaxf(accv, 0.f);
#pragma unroll
  for (int a = 0; a < 5; ++a) {
    float pa = rp * wpo2[l * 5 + a];
#pragma unroll
    for (int m = 32; m >= 1; m >>= 1) pa += __shfl_xor(pa, m);
    if (l == 0) logits[row * 5 + a] = pa + bpo2[a];
  }
  float pv = rv * wv2[l];
#pragma unroll
  for (int m = 32; m >= 1; m >>= 1) pv += __shfl_xor(pv, m);
  if (l == 0) vout[row] = pv + bv2[0];
}

extern "C" void kernel_launch(void* const* d_in, const int* in_sizes, int n_in,
                              void* d_out, int out_size, void* d_ws, size_t ws_size,
                              hipStream_t stream) {
  const float* image = (const float*)d_in[0];
  const float* done = (const float*)d_in[1];
  const float* state0 = (const float*)d_in[2];
  const int* position = (const int*)d_in[3];
  const float* w1 = (const float*)d_in[4];
  const float* b1 = (const float*)d_in[5];
  const float* w2 = (const float*)d_in[6];
  const float* b2 = (const float*)d_in[7];
  const float* w3 = (const float*)d_in[8];
  const float* b3 = (const float*)d_in[9];
  const float* wfc = (const float*)d_in[10];
  const float* bfc = (const float*)d_in[11];
  const float* Ww = (const float*)d_in[12];
  const float* bw = (const float*)d_in[13];
  const float* wp1 = (const float*)d_in[14];
  const float* bp1 = (const float*)d_in[15];
  const float* wp2 = (const float*)d_in[16];
  const float* bp2 = (const float*)d_in[17];
  const float* wpo1 = (const float*)d_in[18];
  const float* bpo1 = (const float*)d_in[19];
  const float* wpo2 = (const float*)d_in[20];
  const float* bpo2 = (const float*)d_in[21];
  const float* wv1 = (const float*)d_in[22];
  const float* bv1 = (const float*)d_in[23];
  const float* wv2 = (const float*)d_in[24];
  const float* bv2 = (const float*)d_in[25];

  float* ws = (float*)d_ws;
  float* w1t = ws + OFF_W1T;
  float* w2t = ws + OFF_W2T;
  float* w3t = ws + OFF_W3T;
  float* wf = ws + OFF_WF;
  float* pfb = ws + OFF_PF;
  float* y0 = ws + OFF_Y0;
  float* ysb = ws + OFF_YS;
  float* h = ws + OFF_H;

  float* out = (float*)d_out;
  float* out_logits = out;            // [2048,5]
  float* out_v = out + 10240;         // [2048,1]
  float* out_state = out + 12288;     // [64,32,16,16]

  // Tier selection by ws_size:
  //  tier1: CS=1024, full c2b, conv3 once.     needs 101.3 MB
  //  tier2: CS=512,  chunked c2b+conv3.        needs 68.9 MB
  //  tier3: CS=256,  chunked c2b+conv3.        needs 50.5 MB
  int tier, CS;
  if (ws_size >= (size_t)25315328 * 4) { tier = 1; CS = 1024; }
  else if (ws_size >= (size_t)17221632 * 4) { tier = 2; CS = 512; }
  else { tier = 3; CS = 256; }
  int nc = TBR / CS;

  float *c2b, *c1b, *c3b;
  if (tier == 1) {
    c2b = ws + OFF_END;                       // [2048][5184]
    c1b = ws + OFF_END + 10616832u;           // [1024][12800]
    c3b = c1b;                                // reuse after chunks done
  } else {
    c2b = ws + OFF_END;                       // [CS][5184]
    c1b = c2b + (size_t)CS * 5184;            // [CS][12800]
    c3b = c1b + (size_t)CS * 12800;           // [2048][3136]
  }

  hipMemsetAsync(y0, 0, 8192 * sizeof(float), stream);
  prep_kernel<<<296, 256, 0, stream>>>(w1, w2, w3, w1t, w2t, w3t);

  for (int c = 0; c < nc; ++c) {
    int n0 = c * CS;
    conv1_kernel<<<dim3(CS * 400 / 256, 2), 256, 0, stream>>>(
        image, w1t, b1, c1b, n0);
    float* c2dst = (tier == 1) ? (c2b + (size_t)n0 * 5184) : c2b;
    conv2_kernel<<<dim3(CS * 81 / 256, 4), 256, 0, stream>>>(
        c1b, w2t, b2, c2dst);
    if (tier != 1) {
      conv3_kernel<<<dim3(CS * 49 / 256, 4), 256, 0, stream>>>(
          c2b, w3t, b3, c3b + (size_t)n0 * 3136);
    }
  }
  if (tier == 1) {
    conv3_kernel<<<dim3(TBR * 49 / 256, 4), 256, 0, stream>>>(
        c2b, w3t, b3, c3b);
  }
  fc_gemm<<<dim3(8, 32), 256, 0, stream>>>(c3b, wfc, bfc, h);
  wfeat_kernel<<<256, 256, 0, stream>>>(h, Ww, bw, wf);
  posfeat_kernel<<<512, 256, 0, stream>>>(position, wp1, bp1, wp2, bp2, pfb);
  y0_kernel<<<256, 256, 0, stream>>>(state0, wpo1, wv1, y0);
  ystate_kernel<<<64, 128, 0, stream>>>(y0, done, position, wf, wpo1, wv1, ysb);
  state_kernel<<<64, 256, 0, stream>>>(state0, done, position, wf, out_state);
  head_kernel<<<512, 256, 0, stream>>>(ysb, pfb, wpo1, wv1, bpo1, bv1,
                                       wpo2, bpo2, wv2, bv2, out_logits, out_v);
}

// Round 5
// 1069.690 us; speedup vs baseline: 2.0549x; 1.0563x over previous
//
#include <hip/hip_runtime.h>
#include <hip/hip_bf16.h>

// MapAgent: NatureCNN (3 convs + FC) -> map-write scan -> policy/value heads.
// T=32, B=64, TB=2048. All fp32.
//
// R5 changes (theory: fc_gemm was occupancy+latency bound — 256 blocks =
// 1 block/CU, Occupancy 11.5%, VALUBusy 21%, and the K-loop issued next-tile
// global loads only after current-tile compute):
//  * fc_gemm v2: BM=32,BN=64,BK=32 -> 512 blocks (2/CU); register prefetch
//    issues next K-tile loads right after the LDS barrier, overlapping
//    global latency with the 256-FMA compute phase.
//  * convs: 32 oc per thread (conv1: one group; conv2/3: blockIdx.y in {0,1})
//    -> 2x FMA per input load issue; acc[32] register-resident (R2-conv1
//    proven pattern). Weights stay provably uniform via blockIdx.y.

#define TT 32
#define BB 64
#define TBR 2048

// ---- workspace offsets (floats) ----
#define OFF_W1T   0u          // 6144   : [ky][kx*3+c][32oc], pre-scaled /255
#define OFF_W2T   6144u       // 32768  : [c*16+tap][oc64]
#define OFF_W3T   38912u      // 36864  : [c*9+tap][oc64]
#define OFF_WF    75776u      // 65536  : wfeat [2048][32]
#define OFF_PF    141312u     // 131072 : posfeat [2048][64]
#define OFF_Y0    272384u     // 8192   : y0 [64][128]
#define OFF_YS    280576u     // 262144 : ystate [2048][128]
#define OFF_H     542720u     // 1048576: h [2048][512]
#define OFF_END   1591296u    // conv buffers laid out per-tier after this

// ---------------- weight prep ----------------
__global__ __launch_bounds__(256) void prep_kernel(
    const float* __restrict__ w1, const float* __restrict__ w2,
    const float* __restrict__ w3, float* __restrict__ w1t,
    float* __restrict__ w2t, float* __restrict__ w3t) {
  int g = blockIdx.x * 256 + threadIdx.x;   // 75776 total
  if (g < 6144) {
    // conv1 k ordering = ky*24 + kx*3 + c ; w1 is [oc][c][ky*8+kx]
    int k = g >> 5, oc = g & 31;
    int c = k % 3, kyx = k / 3;
    w1t[g] = w1[oc * 192 + c * 64 + kyx] * (1.0f / 255.0f);
    return;
  }
  int g2 = g - 6144;
  if (g2 < 32768) {                          // w2t[(c*16+tap)*64+oc]
    int k = g2 >> 6, oc = g2 & 63;
    w2t[g2] = w2[oc * 512 + k];
    return;
  }
  int g3 = g2 - 32768;
  if (g3 < 36864) {                          // w3t[(c*9+tap)*64+oc]
    int k = g3 >> 6, oc = g3 & 63;
    w3t[g3] = w3[oc * 576 + k];
  }
}

// ---------------- conv1: NHWC 84x84x3 -> NCHW [32][20][20], 8x8 s4 ----------
// One thread: one spatial position, all 32 oc (weights loop-uniform).
__global__ __launch_bounds__(256) void conv1_kernel(
    const float* __restrict__ img, const float* __restrict__ w1t,
    const float* __restrict__ b1, float* __restrict__ out, int n0) {
  int gid = blockIdx.x * 256 + threadIdx.x;  // CS*400
  int li = gid / 400;
  int pos = gid - li * 400;
  int oy = pos / 20, ox = pos - (pos / 20) * 20;
  float acc[32];
#pragma unroll
  for (int j = 0; j < 32; ++j) acc[j] = 0.f;
  const float* ib = img + (size_t)(n0 + li) * 21168;
  for (int ky = 0; ky < 8; ++ky) {
    // float offset = 252*(4oy+ky) + 12*ox : multiple of 4 -> 16B aligned
    const float4* rp = (const float4*)(ib + ((4 * oy + ky) * 84 + 4 * ox) * 3);
    float4 r[6];
#pragma unroll
    for (int q = 0; q < 6; ++q) r[q] = rp[q];
    const float* v = (const float*)r;        // 24 floats: kx*3+c
    const float* wk = w1t + ky * 24 * 32;
#pragma unroll
    for (int i = 0; i < 24; ++i) {
      float vv = v[i];
      const float* wr = wk + i * 32;         // uniform -> s_load
#pragma unroll
      for (int j = 0; j < 32; ++j) acc[j] += vv * wr[j];
    }
  }
  float* ob = out + (size_t)li * 12800 + pos;
#pragma unroll
  for (int j = 0; j < 32; ++j)
    ob[j * 400] = fmaxf(acc[j] + b1[j], 0.f);                // coalesced
}

// ---------------- conv2: NCHW [32][20][20] -> [64][9][9], 4x4 s2 ------------
// grid = (CS*81/256, 2); blockIdx.y picks oc group of 32 (SGPR-uniform).
__global__ __launch_bounds__(256) void conv2_kernel(
    const float* __restrict__ in, const float* __restrict__ w2t,
    const float* __restrict__ b2, float* __restrict__ out) {
  int p = blockIdx.x * 256 + threadIdx.x;    // CS*81
  int oc0 = blockIdx.y * 32;                 // SGPR
  int li = p / 81;
  int pos = p - li * 81;
  int oy = pos / 9, ox = pos - (pos / 9) * 9;
  float acc[32];
#pragma unroll
  for (int j = 0; j < 32; ++j) acc[j] = 0.f;
  const float* ib = in + (size_t)li * 12800;
  for (int c = 0; c < 32; ++c) {
#pragma unroll
    for (int ky = 0; ky < 4; ++ky) {
      const float* row = ib + (c * 20 + 2 * oy + ky) * 20 + 2 * ox;
      const float* wk = w2t + (c * 16 + ky * 4) * 64 + oc0;
#pragma unroll
      for (int kx = 0; kx < 4; ++kx) {
        float vv = row[kx];                  // lane-coalesced (stride 2)
        const float* wr = wk + kx * 64;      // uniform -> s_load
#pragma unroll
        for (int j = 0; j < 32; ++j) acc[j] += vv * wr[j];
      }
    }
  }
  float* ob = out + (size_t)li * 5184 + pos;
#pragma unroll
  for (int j = 0; j < 32; ++j)
    ob[(oc0 + j) * 81] = fmaxf(acc[j] + b2[oc0 + j], 0.f);   // coalesced
}

// ---------------- conv3: NCHW [64][9][9] -> [64][7][7], 3x3 s1 --------------
// grid = (count*49/256, 2). Output rows [c*49+pos] = original wfc k-order.
__global__ __launch_bounds__(256) void conv3_kernel(
    const float* __restrict__ in, const float* __restrict__ w3t,
    const float* __restrict__ b3, float* __restrict__ out) {
  int p = blockIdx.x * 256 + threadIdx.x;    // count*49
  int oc0 = blockIdx.y * 32;                 // SGPR
  int li = p / 49;
  int pos = p - li * 49;
  int oy = pos / 7, ox = pos - (pos / 7) * 7;
  float acc[32];
#pragma unroll
  for (int j = 0; j < 32; ++j) acc[j] = 0.f;
  const float* ib = in + (size_t)li * 5184;
  for (int c = 0; c < 64; ++c) {
    const float* rb = ib + (c * 9 + oy) * 9 + ox;
    float v[9];
#pragma unroll
    for (int ky = 0; ky < 3; ++ky) {
#pragma unroll
      for (int kx = 0; kx < 3; ++kx) v[ky * 3 + kx] = rb[ky * 9 + kx];
    }
    const float* wk = w3t + c * 9 * 64 + oc0;
#pragma unroll
    for (int t = 0; t < 9; ++t) {
      float vv = v[t];
      const float* wr = wk + t * 64;         // uniform -> s_load
#pragma unroll
      for (int j = 0; j < 32; ++j) acc[j] += vv * wr[j];
    }
  }
  float* ob = out + (size_t)li * 3136 + pos;
#pragma unroll
  for (int j = 0; j < 32; ++j)
    ob[(oc0 + j) * 49] = fmaxf(acc[j] + b3[oc0 + j], 0.f);   // coalesced
}

// ---------------- FC: [2048,3136] @ [3136,512] + bias, ReLU ----------------
// BM=32, BN=64, BK=32, 256 threads, thread tile 2x4, register prefetch.
// grid (8, 64) = 512 blocks -> 2 blocks/CU.
__global__ __launch_bounds__(256) void fc_gemm(
    const float* __restrict__ A, const float* __restrict__ Bw,
    const float* __restrict__ bias, float* __restrict__ C) {
  __shared__ float As[32][34];   // [k][m], float2-aligned rows
  __shared__ float Bs[32][68];   // [k][n], float4-aligned rows
  int tid = threadIdx.x;
  int m0 = blockIdx.y * 32, n0 = blockIdx.x * 64;
  int tx = tid & 15, ty = tid >> 4;          // output: 2 rows x 4 cols
  int aRow = tid >> 3, aK4 = (tid & 7) * 4;  // A tile 32m x 32k
  int bK = tid >> 4, bN4 = (tid & 15) * 4;   // B tile 32k x 64n (2 halves)
  const float* aPtr = A + (size_t)(m0 + aRow) * 3136 + aK4;
  const float* bPtr = Bw + (size_t)bK * 512 + n0 + bN4;
  float4 aReg = *(const float4*)aPtr;
  float4 bReg0 = *(const float4*)bPtr;
  float4 bReg1 = *(const float4*)(bPtr + 16 * 512);
  float acc[2][4] = {{0.f, 0.f, 0.f, 0.f}, {0.f, 0.f, 0.f, 0.f}};
  for (int k0 = 0; k0 < 3136; k0 += 32) {
    __syncthreads();
    As[aK4][aRow] = aReg.x;
    As[aK4 + 1][aRow] = aReg.y;
    As[aK4 + 2][aRow] = aReg.z;
    As[aK4 + 3][aRow] = aReg.w;
    *(float4*)&Bs[bK][bN4] = bReg0;
    *(float4*)&Bs[bK + 16][bN4] = bReg1;
    __syncthreads();
    if (k0 + 32 < 3136) {                    // prefetch next tile (overlaps
      aReg = *(const float4*)(aPtr + k0 + 32);          //  with compute below)
      bReg0 = *(const float4*)(bPtr + (size_t)(k0 + 32) * 512);
      bReg1 = *(const float4*)(bPtr + (size_t)(k0 + 48) * 512);
    }
#pragma unroll
    for (int kk = 0; kk < 32; ++kk) {
      float2 a = *(const float2*)&As[kk][ty * 2];
      float4 b = *(const float4*)&Bs[kk][tx * 4];
      acc[0][0] += a.x * b.x; acc[0][1] += a.x * b.y;
      acc[0][2] += a.x * b.z; acc[0][3] += a.x * b.w;
      acc[1][0] += a.y * b.x; acc[1][1] += a.y * b.y;
      acc[1][2] += a.y * b.z; acc[1][3] += a.y * b.w;
    }
  }
#pragma unroll
  for (int i = 0; i < 2; ++i) {
#pragma unroll
    for (int j = 0; j < 4; ++j) {
      int m = m0 + ty * 2 + i, n = n0 + tx * 4 + j;
      C[(size_t)m * 512 + n] = fmaxf(acc[i][j] + bias[n], 0.f);
    }
  }
}

// ---------------- wfeat = h @ Ww + bw : [2048,512]@[512,32] ----------------
__global__ __launch_bounds__(256) void wfeat_kernel(
    const float* __restrict__ h, const float* __restrict__ Ww,
    const float* __restrict__ bw, float* __restrict__ wf) {
  int g = blockIdx.x * 256 + threadIdx.x;   // 65536
  int row = g >> 5, oc = g & 31;
  float acc = bw[oc];
  const float* hr = h + (size_t)row * 512;
#pragma unroll 8
  for (int k = 0; k < 512; ++k) acc += hr[k] * Ww[k * 32 + oc];
  wf[g] = acc;
}

// ---------------- posfeat: one-hot MLP, one wave per row ----------------
__global__ __launch_bounds__(256) void posfeat_kernel(
    const int* __restrict__ pos, const float* __restrict__ wp1,
    const float* __restrict__ bp1, const float* __restrict__ wp2,
    const float* __restrict__ bp2, float* __restrict__ pf) {
  int row = (blockIdx.x * 256 + threadIdx.x) >> 6;  // 2048
  int l = threadIdx.x & 63;
  int p0 = pos[row * 2], p1 = pos[row * 2 + 1];
  float t1 = fmaxf(wp1[p0 * 64 + l] + wp1[(16 + p1) * 64 + l] + bp1[l], 0.f);
  float acc = bp2[l];
#pragma unroll
  for (int k = 0; k < 64; ++k) acc += __shfl(t1, k) * wp2[k * 64 + l];
  pf[row * 64 + l] = acc;
}

// ---------------- y0 = state0 @ [wpo1|wv1] : [64,8192]@[8192,128] ----------------
__global__ __launch_bounds__(256) void y0_kernel(
    const float* __restrict__ s0, const float* __restrict__ wpo1,
    const float* __restrict__ wv1, float* __restrict__ y0) {
  int g = blockIdx.x * 256 + threadIdx.x;   // 65536: (b, ks, n)
  int n = g & 127, ks = (g >> 7) & 7, b = g >> 10;
  const float* W = (n < 64) ? (wpo1 + n) : (wv1 + (n - 64));
  const float* s = s0 + (size_t)b * 8192 + ks * 1024;
  float acc = 0.f;
#pragma unroll 4
  for (int j = 0; j < 1024; ++j) acc += s[j] * W[(size_t)(ks * 1024 + j) * 64];
  atomicAdd(y0 + b * 128 + n, acc);
}

// ---------------- ystate: recurrence for hidden@W1 (cols 0..8191) ----------------
__global__ __launch_bounds__(128) void ystate_kernel(
    const float* __restrict__ y0, const float* __restrict__ done,
    const int* __restrict__ pos, const float* __restrict__ wf,
    const float* __restrict__ wpo1, const float* __restrict__ wv1,
    float* __restrict__ ys) {
  int b = blockIdx.x;
  int n = threadIdx.x;                      // 0..127
  const float* W = (n < 64) ? (wpo1 + n) : (wv1 + (n - 64));
  float y = y0[b * 128 + n];
  for (int t = 0; t < TT; ++t) {
    int row = t * BB + b;
    float mask = 1.f - done[row];
    int off = pos[row * 2] * 16 + pos[row * 2 + 1];
    y *= mask;
    const float* wfr = wf + row * 32;
#pragma unroll
    for (int c = 0; c < 32; ++c) y += wfr[c] * W[(size_t)(c * 256 + off) * 64];
    ys[(size_t)row * 128 + n] = y;
  }
}

// ---------------- final map state (output 2) ----------------
__global__ __launch_bounds__(256) void state_kernel(
    const float* __restrict__ s0, const float* __restrict__ done,
    const int* __restrict__ pos, const float* __restrict__ wf,
    float* __restrict__ out_state) {
  int b = blockIdx.x, tid = threadIdx.x;    // tid = spatial offset 0..255
  float s[32];
#pragma unroll
  for (int c = 0; c < 32; ++c) s[c] = s0[(size_t)b * 8192 + c * 256 + tid];
  for (int t = 0; t < TT; ++t) {
    int row = t * BB + b;
    float mask = 1.f - done[row];
    int off = pos[row * 2] * 16 + pos[row * 2 + 1];
#pragma unroll
    for (int c = 0; c < 32; ++c) s[c] *= mask;
    if (tid == off) {
#pragma unroll
      for (int c = 0; c < 32; ++c) s[c] += wf[row * 32 + c];
    }
  }
#pragma unroll
  for (int c = 0; c < 32; ++c) out_state[(size_t)b * 8192 + c * 256 + tid] = s[c];
}

// ---------------- heads: + pos-part of W1, ReLU, second layers ----------------
__global__ __launch_bounds__(256) void head_kernel(
    const float* __restrict__ ys, const float* __restrict__ pf,
    const float* __restrict__ wpo1, const float* __restrict__ wv1,
    const float* __restrict__ bpo1, const float* __restrict__ bv1,
    const float* __restrict__ wpo2, const float* __restrict__ bpo2,
    const float* __restrict__ wv2, const float* __restrict__ bv2,
    float* __restrict__ logits, float* __restrict__ vout) {
  int row = (blockIdx.x * 256 + threadIdx.x) >> 6;  // one wave per row
  int l = threadIdx.x & 63;
  float pfv = pf[row * 64 + l];
  float accp = bpo1[l] + ys[(size_t)row * 128 + l];
  float accv = bv1[l] + ys[(size_t)row * 128 + 64 + l];
#pragma unroll
  for (int k = 0; k < 64; ++k) {
    float pk = __shfl(pfv, k);
    accp += pk * wpo1[(size_t)(8192 + k) * 64 + l];
    accv += pk * wv1[(size_t)(8192 + k) * 64 + l];
  }
  float rp = fmaxf(accp, 0.f), rv = fmaxf(accv, 0.f);
#pragma unroll
  for (int a = 0; a < 5; ++a) {
    float pa = rp * wpo2[l * 5 + a];
#pragma unroll
    for (int m = 32; m >= 1; m >>= 1) pa += __shfl_xor(pa, m);
    if (l == 0) logits[row * 5 + a] = pa + bpo2[a];
  }
  float pv = rv * wv2[l];
#pragma unroll
  for (int m = 32; m >= 1; m >>= 1) pv += __shfl_xor(pv, m);
  if (l == 0) vout[row] = pv + bv2[0];
}

extern "C" void kernel_launch(void* const* d_in, const int* in_sizes, int n_in,
                              void* d_out, int out_size, void* d_ws, size_t ws_size,
                              hipStream_t stream) {
  const float* image = (const float*)d_in[0];
  const float* done = (const float*)d_in[1];
  const float* state0 = (const float*)d_in[2];
  const int* position = (const int*)d_in[3];
  const float* w1 = (const float*)d_in[4];
  const float* b1 = (const float*)d_in[5];
  const float* w2 = (const float*)d_in[6];
  const float* b2 = (const float*)d_in[7];
  const float* w3 = (const float*)d_in[8];
  const float* b3 = (const float*)d_in[9];
  const float* wfc = (const float*)d_in[10];
  const float* bfc = (const float*)d_in[11];
  const float* Ww = (const float*)d_in[12];
  const float* bw = (const float*)d_in[13];
  const float* wp1 = (const float*)d_in[14];
  const float* bp1 = (const float*)d_in[15];
  const float* wp2 = (const float*)d_in[16];
  const float* bp2 = (const float*)d_in[17];
  const float* wpo1 = (const float*)d_in[18];
  const float* bpo1 = (const float*)d_in[19];
  const float* wpo2 = (const float*)d_in[20];
  const float* bpo2 = (const float*)d_in[21];
  const float* wv1 = (const float*)d_in[22];
  const float* bv1 = (const float*)d_in[23];
  const float* wv2 = (const float*)d_in[24];
  const float* bv2 = (const float*)d_in[25];

  float* ws = (float*)d_ws;
  float* w1t = ws + OFF_W1T;
  float* w2t = ws + OFF_W2T;
  float* w3t = ws + OFF_W3T;
  float* wf = ws + OFF_WF;
  float* pfb = ws + OFF_PF;
  float* y0 = ws + OFF_Y0;
  float* ysb = ws + OFF_YS;
  float* h = ws + OFF_H;

  float* out = (float*)d_out;
  float* out_logits = out;            // [2048,5]
  float* out_v = out + 10240;         // [2048,1]
  float* out_state = out + 12288;     // [64,32,16,16]

  // Tier selection by ws_size:
  //  tier1: CS=1024, full c2b, conv3 once.     needs 101.3 MB
  //  tier2: CS=512,  chunked c2b+conv3.        needs 68.9 MB
  //  tier3: CS=256,  chunked c2b+conv3.        needs 50.5 MB
  int tier, CS;
  if (ws_size >= (size_t)25315328 * 4) { tier = 1; CS = 1024; }
  else if (ws_size >= (size_t)17221632 * 4) { tier = 2; CS = 512; }
  else { tier = 3; CS = 256; }
  int nc = TBR / CS;

  float *c2b, *c1b, *c3b;
  if (tier == 1) {
    c2b = ws + OFF_END;                       // [2048][5184]
    c1b = ws + OFF_END + 10616832u;           // [1024][12800]
    c3b = c1b;                                // reuse after chunks done
  } else {
    c2b = ws + OFF_END;                       // [CS][5184]
    c1b = c2b + (size_t)CS * 5184;            // [CS][12800]
    c3b = c1b + (size_t)CS * 12800;           // [2048][3136]
  }

  hipMemsetAsync(y0, 0, 8192 * sizeof(float), stream);
  prep_kernel<<<296, 256, 0, stream>>>(w1, w2, w3, w1t, w2t, w3t);

  for (int c = 0; c < nc; ++c) {
    int n0 = c * CS;
    conv1_kernel<<<CS * 400 / 256, 256, 0, stream>>>(image, w1t, b1, c1b, n0);
    float* c2dst = (tier == 1) ? (c2b + (size_t)n0 * 5184) : c2b;
    conv2_kernel<<<dim3(CS * 81 / 256, 2), 256, 0, stream>>>(
        c1b, w2t, b2, c2dst);
    if (tier != 1) {
      conv3_kernel<<<dim3(CS * 49 / 256, 2), 256, 0, stream>>>(
          c2b, w3t, b3, c3b + (size_t)n0 * 3136);
    }
  }
  if (tier == 1) {
    conv3_kernel<<<dim3(TBR * 49 / 256, 2), 256, 0, stream>>>(
        c2b, w3t, b3, c3b);
  }
  fc_gemm<<<dim3(8, 64), 256, 0, stream>>>(c3b, wfc, bfc, h);
  wfeat_kernel<<<256, 256, 0, stream>>>(h, Ww, bw, wf);
  posfeat_kernel<<<512, 256, 0, stream>>>(position, wp1, bp1, wp2, bp2, pfb);
  y0_kernel<<<256, 256, 0, stream>>>(state0, wpo1, wv1, y0);
  ystate_kernel<<<64, 128, 0, stream>>>(y0, done, position, wf, wpo1, wv1, ysb);
  state_kernel<<<64, 256, 0, stream>>>(state0, done, position, wf, out_state);
  head_kernel<<<512, 256, 0, stream>>>(ysb, pfb, wpo1, wv1, bpo1, bv1,
                                       wpo2, bpo2, wv2, bv2, out_logits, out_v);
}

// Round 6
// 973.514 us; speedup vs baseline: 2.2579x; 1.0988x over previous
//
#include <hip/hip_runtime.h>
#include <hip/hip_bf16.h>

// MapAgent: NatureCNN (3 convs + FC) -> map-write scan -> policy/value heads.
// T=32, B=64, TB=2048.
//
// R6 changes (theory: fc_gemm fp32 was LDS-throughput bound — 8 FMA vs
// b64+b128 reads per kk, VALUBusy 52%, 1.6M bank conflicts; fp32 floor 42us.
// absmax 9.8e-4 vs threshold 1.7e-2 leaves precision headroom):
//  * fc -> fp16 MFMA (mfma_f32_16x16x32_f16, fp32 accumulate). conv3 emits
//    fp16 (FC is its only consumer); prep transposes wfc -> wfcT fp16
//    (B^T layout: k contiguous per n — m92-verified fragment pattern).
//  * fc_mfma: 64x64 tile, 4 waves, BK=32, LDS row stride 40 halves
//    (16B-aligned b128 frags, <=2-way bank alias = free), reg prefetch.
//  * expected fp16-induced error ~1e-3 (inputs O(1), weights ~1/56, K=3136).

#define TT 32
#define BB 64
#define TBR 2048

typedef _Float16 half_t;
typedef __attribute__((ext_vector_type(8))) _Float16 half8;
typedef __attribute__((ext_vector_type(4))) float f32x4;

// ---- workspace offsets (floats) ----
#define OFF_W1T   0u          // 6144   : [ky][kx*3+c][32oc], pre-scaled /255
#define OFF_W2T   6144u       // 32768  : [c*16+tap][oc64]
#define OFF_W3T   38912u      // 36864  : [c*9+tap][oc64]
#define OFF_WF    75776u      // 65536  : wfeat [2048][32]
#define OFF_PF    141312u     // 131072 : posfeat [2048][64]
#define OFF_Y0    272384u     // 8192   : y0 [64][128]
#define OFF_YS    280576u     // 262144 : ystate [2048][128]
#define OFF_H     542720u     // 1048576: h [2048][512]
#define OFF_WFCT  1591296u    // 802816 : wfcT [512][3136] fp16 (half of floats)
#define OFF_END   2394112u    // conv buffers laid out per-tier after this

// ---------------- weight prep ----------------
__global__ __launch_bounds__(256) void prep_kernel(
    const float* __restrict__ w1, const float* __restrict__ w2,
    const float* __restrict__ w3, float* __restrict__ w1t,
    float* __restrict__ w2t, float* __restrict__ w3t) {
  int g = blockIdx.x * 256 + threadIdx.x;   // 75776 total
  if (g < 6144) {
    // conv1 k ordering = ky*24 + kx*3 + c ; w1 is [oc][c][ky*8+kx]
    int k = g >> 5, oc = g & 31;
    int c = k % 3, kyx = k / 3;
    w1t[g] = w1[oc * 192 + c * 64 + kyx] * (1.0f / 255.0f);
    return;
  }
  int g2 = g - 6144;
  if (g2 < 32768) {                          // w2t[(c*16+tap)*64+oc]
    int k = g2 >> 6, oc = g2 & 63;
    w2t[g2] = w2[oc * 512 + k];
    return;
  }
  int g3 = g2 - 32768;
  if (g3 < 36864) {                          // w3t[(c*9+tap)*64+oc]
    int k = g3 >> 6, oc = g3 & 63;
    w3t[g3] = w3[oc * 576 + k];
  }
}

// ---- wfcT[n][k] = (half)wfc[k][n] : LDS-tiled 32x32 transpose ----
__global__ __launch_bounds__(256) void prep_wfct(
    const float* __restrict__ wfc, half_t* __restrict__ wfcT) {
  __shared__ float t[32][33];
  int k0 = blockIdx.x * 32, n0 = blockIdx.y * 32;
  int tx = threadIdx.x & 31, ty = threadIdx.x >> 5;  // ty 0..7
#pragma unroll
  for (int i = 0; i < 4; ++i)
    t[ty + 8 * i][tx] = wfc[(size_t)(k0 + ty + 8 * i) * 512 + n0 + tx];
  __syncthreads();
#pragma unroll
  for (int i = 0; i < 4; ++i)
    wfcT[(size_t)(n0 + ty + 8 * i) * 3136 + k0 + tx] =
        (half_t)t[tx][ty + 8 * i];
}

// ---------------- conv1: NHWC 84x84x3 -> NCHW [32][20][20], 8x8 s4 ----------
__global__ __launch_bounds__(256) void conv1_kernel(
    const float* __restrict__ img, const float* __restrict__ w1t,
    const float* __restrict__ b1, float* __restrict__ out, int n0) {
  int gid = blockIdx.x * 256 + threadIdx.x;  // CS*400
  int li = gid / 400;
  int pos = gid - li * 400;
  int oy = pos / 20, ox = pos - (pos / 20) * 20;
  float acc[32];
#pragma unroll
  for (int j = 0; j < 32; ++j) acc[j] = 0.f;
  const float* ib = img + (size_t)(n0 + li) * 21168;
  for (int ky = 0; ky < 8; ++ky) {
    // float offset = 252*(4oy+ky) + 12*ox : multiple of 4 -> 16B aligned
    const float4* rp = (const float4*)(ib + ((4 * oy + ky) * 84 + 4 * ox) * 3);
    float4 r[6];
#pragma unroll
    for (int q = 0; q < 6; ++q) r[q] = rp[q];
    const float* v = (const float*)r;        // 24 floats: kx*3+c
    const float* wk = w1t + ky * 24 * 32;
#pragma unroll
    for (int i = 0; i < 24; ++i) {
      float vv = v[i];
      const float* wr = wk + i * 32;         // uniform -> s_load
#pragma unroll
      for (int j = 0; j < 32; ++j) acc[j] += vv * wr[j];
    }
  }
  float* ob = out + (size_t)li * 12800 + pos;
#pragma unroll
  for (int j = 0; j < 32; ++j)
    ob[j * 400] = fmaxf(acc[j] + b1[j], 0.f);                // coalesced
}

// ---------------- conv2: NCHW [32][20][20] -> [64][9][9], 4x4 s2 ------------
__global__ __launch_bounds__(256) void conv2_kernel(
    const float* __restrict__ in, const float* __restrict__ w2t,
    const float* __restrict__ b2, float* __restrict__ out) {
  int p = blockIdx.x * 256 + threadIdx.x;    // CS*81
  int oc0 = blockIdx.y * 32;                 // SGPR
  int li = p / 81;
  int pos = p - li * 81;
  int oy = pos / 9, ox = pos - (pos / 9) * 9;
  float acc[32];
#pragma unroll
  for (int j = 0; j < 32; ++j) acc[j] = 0.f;
  const float* ib = in + (size_t)li * 12800;
  for (int c = 0; c < 32; ++c) {
#pragma unroll
    for (int ky = 0; ky < 4; ++ky) {
      const float* row = ib + (c * 20 + 2 * oy + ky) * 20 + 2 * ox;
      const float* wk = w2t + (c * 16 + ky * 4) * 64 + oc0;
#pragma unroll
      for (int kx = 0; kx < 4; ++kx) {
        float vv = row[kx];                  // lane-coalesced (stride 2)
        const float* wr = wk + kx * 64;      // uniform -> s_load
#pragma unroll
        for (int j = 0; j < 32; ++j) acc[j] += vv * wr[j];
      }
    }
  }
  float* ob = out + (size_t)li * 5184 + pos;
#pragma unroll
  for (int j = 0; j < 32; ++j)
    ob[(oc0 + j) * 81] = fmaxf(acc[j] + b2[oc0 + j], 0.f);   // coalesced
}

// ---------------- conv3: NCHW [64][9][9] -> fp16 [64][7][7], 3x3 s1 ---------
// Output rows [c*49+pos] per image, fp16 (feeds fc_mfma only).
__global__ __launch_bounds__(256) void conv3_kernel(
    const float* __restrict__ in, const float* __restrict__ w3t,
    const float* __restrict__ b3, half_t* __restrict__ out) {
  int p = blockIdx.x * 256 + threadIdx.x;    // count*49
  int oc0 = blockIdx.y * 32;                 // SGPR
  int li = p / 49;
  int pos = p - li * 49;
  int oy = pos / 7, ox = pos - (pos / 7) * 7;
  float acc[32];
#pragma unroll
  for (int j = 0; j < 32; ++j) acc[j] = 0.f;
  const float* ib = in + (size_t)li * 5184;
  for (int c = 0; c < 64; ++c) {
    const float* rb = ib + (c * 9 + oy) * 9 + ox;
    float v[9];
#pragma unroll
    for (int ky = 0; ky < 3; ++ky) {
#pragma unroll
      for (int kx = 0; kx < 3; ++kx) v[ky * 3 + kx] = rb[ky * 9 + kx];
    }
    const float* wk = w3t + c * 9 * 64 + oc0;
#pragma unroll
    for (int t = 0; t < 9; ++t) {
      float vv = v[t];
      const float* wr = wk + t * 64;         // uniform -> s_load
#pragma unroll
      for (int j = 0; j < 32; ++j) acc[j] += vv * wr[j];
    }
  }
  half_t* ob = out + (size_t)li * 3136 + pos;
#pragma unroll
  for (int j = 0; j < 32; ++j)
    ob[(oc0 + j) * 49] = (half_t)fmaxf(acc[j] + b3[oc0 + j], 0.f);
}

// ---------------- FC via MFMA: h = relu(A[2048,3136] @ wfc + bfc) -----------
// A fp16 (conv3 out), Bt = wfcT fp16 [512][3136]. 64x64 tile, 4 waves,
// BK=32. LDS rows padded to 40 halves (16B-aligned b128 frag reads).
// C/D mapping: col=lane&15, row=(lane>>4)*4+reg  [m89-verified].
__global__ __launch_bounds__(256) void fc_mfma(
    const half_t* __restrict__ A, const half_t* __restrict__ Bt,
    const float* __restrict__ bias, float* __restrict__ C) {
  __shared__ __align__(16) half_t As[64 * 40];
  __shared__ __align__(16) half_t Bs[64 * 40];
  int tid = threadIdx.x;
  int m0 = blockIdx.y * 64, n0 = blockIdx.x * 64;
  int w = tid >> 6;                          // wave 0..3 -> m subtile
  int l = tid & 63;
  int lc = l & 15, q = l >> 4;               // frag lane coords
  int srow = tid >> 2, sseg = tid & 3;       // staging: 64 rows x 4 segs

  const half_t* aPtr = A + (size_t)(m0 + srow) * 3136 + sseg * 8;
  const half_t* bPtr = Bt + (size_t)(n0 + srow) * 3136 + sseg * 8;
  uint4 aReg = *(const uint4*)aPtr;
  uint4 bReg = *(const uint4*)bPtr;

  f32x4 acc[4];
#pragma unroll
  for (int t = 0; t < 4; ++t) acc[t] = (f32x4){0.f, 0.f, 0.f, 0.f};

  for (int k0 = 0; k0 < 3136; k0 += 32) {
    __syncthreads();
    *(uint4*)&As[srow * 40 + sseg * 8] = aReg;
    *(uint4*)&Bs[srow * 40 + sseg * 8] = bReg;
    __syncthreads();
    if (k0 + 32 < 3136) {                    // prefetch overlaps MFMA below
      aReg = *(const uint4*)(aPtr + k0 + 32);
      bReg = *(const uint4*)(bPtr + k0 + 32);
    }
    half8 af = *(const half8*)&As[(w * 16 + lc) * 40 + q * 8];
#pragma unroll
    for (int t = 0; t < 4; ++t) {
      half8 bf = *(const half8*)&Bs[(t * 16 + lc) * 40 + q * 8];
      acc[t] = __builtin_amdgcn_mfma_f32_16x16x32_f16(af, bf, acc[t], 0, 0, 0);
    }
  }
#pragma unroll
  for (int t = 0; t < 4; ++t) {
#pragma unroll
    for (int r = 0; r < 4; ++r) {
      int row = m0 + w * 16 + q * 4 + r;
      int col = n0 + t * 16 + lc;
      C[(size_t)row * 512 + col] = fmaxf(acc[t][r] + bias[col], 0.f);
    }
  }
}

// ---------------- wfeat = h @ Ww + bw : [2048,512]@[512,32] ----------------
__global__ __launch_bounds__(256) void wfeat_kernel(
    const float* __restrict__ h, const float* __restrict__ Ww,
    const float* __restrict__ bw, float* __restrict__ wf) {
  int g = blockIdx.x * 256 + threadIdx.x;   // 65536
  int row = g >> 5, oc = g & 31;
  float acc = bw[oc];
  const float* hr = h + (size_t)row * 512;
#pragma unroll 8
  for (int k = 0; k < 512; ++k) acc += hr[k] * Ww[k * 32 + oc];
  wf[g] = acc;
}

// ---------------- posfeat: one-hot MLP, one wave per row ----------------
__global__ __launch_bounds__(256) void posfeat_kernel(
    const int* __restrict__ pos, const float* __restrict__ wp1,
    const float* __restrict__ bp1, const float* __restrict__ wp2,
    const float* __restrict__ bp2, float* __restrict__ pf) {
  int row = (blockIdx.x * 256 + threadIdx.x) >> 6;  // 2048
  int l = threadIdx.x & 63;
  int p0 = pos[row * 2], p1 = pos[row * 2 + 1];
  float t1 = fmaxf(wp1[p0 * 64 + l] + wp1[(16 + p1) * 64 + l] + bp1[l], 0.f);
  float acc = bp2[l];
#pragma unroll
  for (int k = 0; k < 64; ++k) acc += __shfl(t1, k) * wp2[k * 64 + l];
  pf[row * 64 + l] = acc;
}

// ---------------- y0 = state0 @ [wpo1|wv1] : [64,8192]@[8192,128] ----------------
__global__ __launch_bounds__(256) void y0_kernel(
    const float* __restrict__ s0, const float* __restrict__ wpo1,
    const float* __restrict__ wv1, float* __restrict__ y0) {
  int g = blockIdx.x * 256 + threadIdx.x;   // 65536: (b, ks, n)
  int n = g & 127, ks = (g >> 7) & 7, b = g >> 10;
  const float* W = (n < 64) ? (wpo1 + n) : (wv1 + (n - 64));
  const float* s = s0 + (size_t)b * 8192 + ks * 1024;
  float acc = 0.f;
#pragma unroll 4
  for (int j = 0; j < 1024; ++j) acc += s[j] * W[(size_t)(ks * 1024 + j) * 64];
  atomicAdd(y0 + b * 128 + n, acc);
}

// ---------------- ystate: recurrence for hidden@W1 (cols 0..8191) ----------------
__global__ __launch_bounds__(128) void ystate_kernel(
    const float* __restrict__ y0, const float* __restrict__ done,
    const int* __restrict__ pos, const float* __restrict__ wf,
    const float* __restrict__ wpo1, const float* __restrict__ wv1,
    float* __restrict__ ys) {
  int b = blockIdx.x;
  int n = threadIdx.x;                      // 0..127
  const float* W = (n < 64) ? (wpo1 + n) : (wv1 + (n - 64));
  float y = y0[b * 128 + n];
  for (int t = 0; t < TT; ++t) {
    int row = t * BB + b;
    float mask = 1.f - done[row];
    int off = pos[row * 2] * 16 + pos[row * 2 + 1];
    y *= mask;
    const float* wfr = wf + row * 32;
#pragma unroll
    for (int c = 0; c < 32; ++c) y += wfr[c] * W[(size_t)(c * 256 + off) * 64];
    ys[(size_t)row * 128 + n] = y;
  }
}

// ---------------- final map state (output 2) ----------------
__global__ __launch_bounds__(256) void state_kernel(
    const float* __restrict__ s0, const float* __restrict__ done,
    const int* __restrict__ pos, const float* __restrict__ wf,
    float* __restrict__ out_state) {
  int b = blockIdx.x, tid = threadIdx.x;    // tid = spatial offset 0..255
  float s[32];
#pragma unroll
  for (int c = 0; c < 32; ++c) s[c] = s0[(size_t)b * 8192 + c * 256 + tid];
  for (int t = 0; t < TT; ++t) {
    int row = t * BB + b;
    float mask = 1.f - done[row];
    int off = pos[row * 2] * 16 + pos[row * 2 + 1];
#pragma unroll
    for (int c = 0; c < 32; ++c) s[c] *= mask;
    if (tid == off) {
#pragma unroll
      for (int c = 0; c < 32; ++c) s[c] += wf[row * 32 + c];
    }
  }
#pragma unroll
  for (int c = 0; c < 32; ++c) out_state[(size_t)b * 8192 + c * 256 + tid] = s[c];
}

// ---------------- heads: + pos-part of W1, ReLU, second layers ----------------
__global__ __launch_bounds__(256) void head_kernel(
    const float* __restrict__ ys, const float* __restrict__ pf,
    const float* __restrict__ wpo1, const float* __restrict__ wv1,
    const float* __restrict__ bpo1, const float* __restrict__ bv1,
    const float* __restrict__ wpo2, const float* __restrict__ bpo2,
    const float* __restrict__ wv2, const float* __restrict__ bv2,
    float* __restrict__ logits, float* __restrict__ vout) {
  int row = (blockIdx.x * 256 + threadIdx.x) >> 6;  // one wave per row
  int l = threadIdx.x & 63;
  float pfv = pf[row * 64 + l];
  float accp = bpo1[l] + ys[(size_t)row * 128 + l];
  float accv = bv1[l] + ys[(size_t)row * 128 + 64 + l];
#pragma unroll
  for (int k = 0; k < 64; ++k) {
    float pk = __shfl(pfv, k);
    accp += pk * wpo1[(size_t)(8192 + k) * 64 + l];
    accv += pk * wv1[(size_t)(8192 + k) * 64 + l];
  }
  float rp = fmaxf(accp, 0.f), rv = fmaxf(accv, 0.f);
#pragma unroll
  for (int a = 0; a < 5; ++a) {
    float pa = rp * wpo2[l * 5 + a];
#pragma unroll
    for (int m = 32; m >= 1; m >>= 1) pa += __shfl_xor(pa, m);
    if (l == 0) logits[row * 5 + a] = pa + bpo2[a];
  }
  float pv = rv * wv2[l];
#pragma unroll
  for (int m = 32; m >= 1; m >>= 1) pv += __shfl_xor(pv, m);
  if (l == 0) vout[row] = pv + bv2[0];
}

extern "C" void kernel_launch(void* const* d_in, const int* in_sizes, int n_in,
                              void* d_out, int out_size, void* d_ws, size_t ws_size,
                              hipStream_t stream) {
  const float* image = (const float*)d_in[0];
  const float* done = (const float*)d_in[1];
  const float* state0 = (const float*)d_in[2];
  const int* position = (const int*)d_in[3];
  const float* w1 = (const float*)d_in[4];
  const float* b1 = (const float*)d_in[5];
  const float* w2 = (const float*)d_in[6];
  const float* b2 = (const float*)d_in[7];
  const float* w3 = (const float*)d_in[8];
  const float* b3 = (const float*)d_in[9];
  const float* wfc = (const float*)d_in[10];
  const float* bfc = (const float*)d_in[11];
  const float* Ww = (const float*)d_in[12];
  const float* bw = (const float*)d_in[13];
  const float* wp1 = (const float*)d_in[14];
  const float* bp1 = (const float*)d_in[15];
  const float* wp2 = (const float*)d_in[16];
  const float* bp2 = (const float*)d_in[17];
  const float* wpo1 = (const float*)d_in[18];
  const float* bpo1 = (const float*)d_in[19];
  const float* wpo2 = (const float*)d_in[20];
  const float* bpo2 = (const float*)d_in[21];
  const float* wv1 = (const float*)d_in[22];
  const float* bv1 = (const float*)d_in[23];
  const float* wv2 = (const float*)d_in[24];
  const float* bv2 = (const float*)d_in[25];

  float* ws = (float*)d_ws;
  float* w1t = ws + OFF_W1T;
  float* w2t = ws + OFF_W2T;
  float* w3t = ws + OFF_W3T;
  float* wf = ws + OFF_WF;
  float* pfb = ws + OFF_PF;
  float* y0 = ws + OFF_Y0;
  float* ysb = ws + OFF_YS;
  float* h = ws + OFF_H;
  half_t* wfcT = (half_t*)(ws + OFF_WFCT);

  float* out = (float*)d_out;
  float* out_logits = out;            // [2048,5]
  float* out_v = out + 10240;         // [2048,1]
  float* out_state = out + 12288;     // [64,32,16,16]

  // Tier selection by ws_size (floats incl. wfcT):
  //  tier1: CS=1024, full c2b, conv3 once.     needs 104.5 MB
  //  tier2: CS=512,  chunked c2b+conv3.        needs 52.9 MB
  //  tier3: CS=256,  chunked c2b+conv3.        needs 34.5 MB
  int tier, CS;
  if (ws_size >= (size_t)26118144 * 4) { tier = 1; CS = 1024; }
  else if (ws_size >= (size_t)13207552 * 4) { tier = 2; CS = 512; }
  else { tier = 3; CS = 256; }
  int nc = TBR / CS;

  float *c2b, *c1b;
  half_t* c3b;
  if (tier == 1) {
    c2b = ws + OFF_END;                       // [2048][5184] f32
    c1b = ws + OFF_END + 10616832u;           // [1024][12800] f32
    c3b = (half_t*)c1b;                       // [2048][3136] f16, reuse
  } else {
    c2b = ws + OFF_END;                       // [CS][5184] f32
    c1b = c2b + (size_t)CS * 5184;            // [CS][12800] f32
    c3b = (half_t*)(c1b + (size_t)CS * 12800);// [2048][3136] f16
  }

  hipMemsetAsync(y0, 0, 8192 * sizeof(float), stream);
  prep_kernel<<<296, 256, 0, stream>>>(w1, w2, w3, w1t, w2t, w3t);
  prep_wfct<<<dim3(98, 16), 256, 0, stream>>>(wfc, wfcT);

  for (int c = 0; c < nc; ++c) {
    int n0 = c * CS;
    conv1_kernel<<<CS * 400 / 256, 256, 0, stream>>>(image, w1t, b1, c1b, n0);
    float* c2dst = (tier == 1) ? (c2b + (size_t)n0 * 5184) : c2b;
    conv2_kernel<<<dim3(CS * 81 / 256, 2), 256, 0, stream>>>(
        c1b, w2t, b2, c2dst);
    if (tier != 1) {
      conv3_kernel<<<dim3(CS * 49 / 256, 2), 256, 0, stream>>>(
          c2b, w3t, b3, c3b + (size_t)n0 * 3136);
    }
  }
  if (tier == 1) {
    conv3_kernel<<<dim3(TBR * 49 / 256, 2), 256, 0, stream>>>(
        c2b, w3t, b3, c3b);
  }
  fc_mfma<<<dim3(8, 32), 256, 0, stream>>>(c3b, wfcT, bfc, h);
  wfeat_kernel<<<256, 256, 0, stream>>>(h, Ww, bw, wf);
  posfeat_kernel<<<512, 256, 0, stream>>>(position, wp1, bp1, wp2, bp2, pfb);
  y0_kernel<<<256, 256, 0, stream>>>(state0, wpo1, wv1, y0);
  ystate_kernel<<<64, 128, 0, stream>>>(y0, done, position, wf, wpo1, wv1, ysb);
  state_kernel<<<64, 256, 0, stream>>>(state0, done, position, wf, out_state);
  head_kernel<<<512, 256, 0, stream>>>(ysb, pfb, wpo1, wv1, bpo1, bv1,
                                       wpo2, bpo2, wv2, bv2, out_logits, out_v);
}

// Round 7
// 677.873 us; speedup vs baseline: 3.2427x; 1.4361x over previous
//
#include <hip/hip_runtime.h>
#include <hip/hip_bf16.h>

// MapAgent: NatureCNN (3 convs + FC) -> map-write scan -> policy/value heads.
// T=32, B=64, TB=2048.
//
// R7 changes (theory: conv3 fp32-VALU was strip-mined (VGPR=32 < acc[32]+v[9])
// and floors at 47us anyway; conv2 at 69us. All convs are GEMMs):
//  * conv2/conv3 -> implicit-GEMM fp16 MFMA over taps: channels-last
//    activations make each A-tile row a contiguous pixel vector. Same
//    LDS-staging/fragment pattern as the R6-proven fc_mfma.
//    conv2: 16 taps x K=32. conv3: 9 taps x 2 chunks x K=32.
//  * conv1 stays fp32 VALU (scalar-path weights) but emits fp16
//    channels-last [li][y][x][32] (64B contiguous store per thread).
//  * conv3 epilogue writes k-order c*49+pos -> fc_mfma/wfcT unchanged (R6).
//  * w2/w3 prepped as fp16 B^T tiles [tap][oc][c].

#define TT 32
#define BB 64
#define TBR 2048

typedef _Float16 half_t;
typedef __attribute__((ext_vector_type(8))) _Float16 half8;
typedef __attribute__((ext_vector_type(4))) float f32x4;

// ---- workspace offsets (floats) ----
#define OFF_W1T   0u          // 6144    : conv1 w [ky][kx*3+c][32oc] f32, /255
#define OFF_W2T   6144u       // 16384   : w2T fp16 [tap16][oc64][c32]
#define OFF_W3T   22528u      // 18432   : w3T fp16 [tap9][oc64][c64]
#define OFF_WF    40960u      // 65536   : wfeat [2048][32]
#define OFF_PF    106496u     // 131072  : posfeat [2048][64]
#define OFF_Y0    237568u     // 8192    : y0 [64][128]
#define OFF_YS    245760u     // 262144  : ystate [2048][128]
#define OFF_H     507904u     // 1048576 : h [2048][512]
#define OFF_WFCT  1556480u    // 802816  : wfcT fp16 [512][3136] (k=c*49+pos)
#define OFF_C3    2359296u    // 3211264 : c3b fp16 [2048][3136]
#define OFF_C2    5570560u    // 5308416 : c2b fp16 [2048][9][9][64]
#define OFF_C1    10878976u   // c1b fp16 [CS][20][20][32]

// ---------------- weight prep ----------------
__global__ __launch_bounds__(256) void prep_kernel(
    const float* __restrict__ w1, const float* __restrict__ w2,
    const float* __restrict__ w3, float* __restrict__ w1t,
    half_t* __restrict__ w2T, half_t* __restrict__ w3T) {
  int g = blockIdx.x * 256 + threadIdx.x;   // 75776 total
  if (g < 6144) {
    // conv1 k ordering = ky*24 + kx*3 + c ; w1 is [oc][c][ky*8+kx]
    int k = g >> 5, oc = g & 31;
    int c = k % 3, kyx = k / 3;
    w1t[g] = w1[oc * 192 + c * 64 + kyx] * (1.0f / 255.0f);
    return;
  }
  int g2 = g - 6144;
  if (g2 < 32768) {                          // w2T[(tap*64+oc)*32+c]
    int c = g2 & 31, oc = (g2 >> 5) & 63, tap = g2 >> 11;
    w2T[g2] = (half_t)w2[oc * 512 + c * 16 + tap];
    return;
  }
  int g3 = g2 - 32768;
  if (g3 < 36864) {                          // w3T[(tap*64+oc)*64+c]
    int c = g3 & 63, oc = (g3 >> 6) & 63, tap = g3 >> 12;
    w3T[g3] = (half_t)w3[oc * 576 + c * 9 + tap];
  }
}

// ---- wfcT[n][k] = (half)wfc[k][n], k = c*49+pos : LDS-tiled transpose ----
__global__ __launch_bounds__(256) void prep_wfct(
    const float* __restrict__ wfc, half_t* __restrict__ wfcT) {
  __shared__ float t[32][33];
  int k0 = blockIdx.x * 32, n0 = blockIdx.y * 32;
  int tx = threadIdx.x & 31, ty = threadIdx.x >> 5;  // ty 0..7
#pragma unroll
  for (int i = 0; i < 4; ++i)
    t[ty + 8 * i][tx] = wfc[(size_t)(k0 + ty + 8 * i) * 512 + n0 + tx];
  __syncthreads();
#pragma unroll
  for (int i = 0; i < 4; ++i)
    wfcT[(size_t)(n0 + ty + 8 * i) * 3136 + k0 + tx] =
        (half_t)t[tx][ty + 8 * i];
}

// ---------------- conv1: NHWC 84x84x3 -> fp16 [li][20][20][32], 8x8 s4 ------
__global__ __launch_bounds__(256) void conv1_kernel(
    const float* __restrict__ img, const float* __restrict__ w1t,
    const float* __restrict__ b1, half_t* __restrict__ out, int n0) {
  int gid = blockIdx.x * 256 + threadIdx.x;  // CS*400
  int li = gid / 400;
  int pos = gid - li * 400;
  int oy = pos / 20, ox = pos - (pos / 20) * 20;
  float acc[32];
#pragma unroll
  for (int j = 0; j < 32; ++j) acc[j] = 0.f;
  const float* ib = img + (size_t)(n0 + li) * 21168;
  for (int ky = 0; ky < 8; ++ky) {
    // float offset = 252*(4oy+ky) + 12*ox : multiple of 4 -> 16B aligned
    const float4* rp = (const float4*)(ib + ((4 * oy + ky) * 84 + 4 * ox) * 3);
    float4 r[6];
#pragma unroll
    for (int q = 0; q < 6; ++q) r[q] = rp[q];
    const float* v = (const float*)r;        // 24 floats: kx*3+c
    const float* wk = w1t + ky * 24 * 32;
#pragma unroll
    for (int i = 0; i < 24; ++i) {
      float vv = v[i];
      const float* wr = wk + i * 32;         // uniform -> s_load
#pragma unroll
      for (int j = 0; j < 32; ++j) acc[j] += vv * wr[j];
    }
  }
  half_t* ob = out + (size_t)(li * 400 + pos) * 32;   // 64B contiguous/thread
#pragma unroll
  for (int v8 = 0; v8 < 4; ++v8) {
    half8 o;
#pragma unroll
    for (int j = 0; j < 8; ++j)
      o[j] = (half_t)fmaxf(acc[v8 * 8 + j] + b1[v8 * 8 + j], 0.f);
    *(half8*)(ob + v8 * 8) = o;
  }
}

// ---------------- conv2 implicit-GEMM MFMA: -> fp16 [li][9][9][64] ----------
// M-tile 64 x N=64, 4 waves, 16 taps x K=32. A row = in[li][2oy+ky][2ox+kx][:].
__global__ __launch_bounds__(256) void conv2_mfma(
    const half_t* __restrict__ in, const half_t* __restrict__ w2T,
    const float* __restrict__ b2, half_t* __restrict__ out) {
  __shared__ __align__(16) half_t As[64 * 40];
  __shared__ __align__(16) half_t Bs[64 * 40];
  int tid = threadIdx.x;
  int m0 = blockIdx.x * 64;
  int w = tid >> 6, l = tid & 63, lc = l & 15, q = l >> 4;
  int srow = tid >> 2, sseg = tid & 3;
  int m = m0 + srow;
  int li = m / 81, pos = m - li * 81;
  int oy = pos / 9, ox = pos - (pos / 9) * 9;
  const half_t* aBase = in + (size_t)((li * 20 + 2 * oy) * 20 + 2 * ox) * 32 + sseg * 8;
  const half_t* bBase = w2T + srow * 32 + sseg * 8;
  uint4 aReg = *(const uint4*)aBase;          // tap 0
  uint4 bReg = *(const uint4*)bBase;
  f32x4 acc[4];
#pragma unroll
  for (int t = 0; t < 4; ++t) acc[t] = (f32x4){0.f, 0.f, 0.f, 0.f};
#pragma unroll
  for (int tap = 0; tap < 16; ++tap) {
    __syncthreads();
    *(uint4*)&As[srow * 40 + sseg * 8] = aReg;
    *(uint4*)&Bs[srow * 40 + sseg * 8] = bReg;
    __syncthreads();
    if (tap < 15) {                           // prefetch next tap
      int nt = tap + 1, ky = nt >> 2, kx = nt & 3;
      aReg = *(const uint4*)(aBase + (ky * 20 + kx) * 32);
      bReg = *(const uint4*)(bBase + nt * 2048);
    }
    half8 af = *(const half8*)&As[(w * 16 + lc) * 40 + q * 8];
#pragma unroll
    for (int t = 0; t < 4; ++t) {
      half8 bf = *(const half8*)&Bs[(t * 16 + lc) * 40 + q * 8];
      acc[t] = __builtin_amdgcn_mfma_f32_16x16x32_f16(af, bf, acc[t], 0, 0, 0);
    }
  }
  // C: row=w*16+q*4+r, col=t*16+lc [m89]; out offset = m*64+col (layout [m][c])
#pragma unroll
  for (int t = 0; t < 4; ++t) {
#pragma unroll
    for (int r = 0; r < 4; ++r) {
      int mr = m0 + w * 16 + q * 4 + r;
      int col = t * 16 + lc;
      out[(size_t)mr * 64 + col] = (half_t)fmaxf(acc[t][r] + b2[col], 0.f);
    }
  }
}

// ---------------- conv3 implicit-GEMM MFMA: -> fp16 [li][c*49+pos] ----------
// M-tile 64 x N=64, 9 taps x 2 chunks x K=32. A row = in[li][oy+ky][ox+kx][:].
__global__ __launch_bounds__(256) void conv3_mfma(
    const half_t* __restrict__ in, const half_t* __restrict__ w3T,
    const float* __restrict__ b3, half_t* __restrict__ out) {
  __shared__ __align__(16) half_t As[64 * 40];
  __shared__ __align__(16) half_t Bs[64 * 40];
  int tid = threadIdx.x;
  int m0 = blockIdx.x * 64;
  int w = tid >> 6, l = tid & 63, lc = l & 15, q = l >> 4;
  int srow = tid >> 2, sseg = tid & 3;
  int m = m0 + srow;
  int li = m / 49, pos = m - li * 49;
  int oy = pos / 7, ox = pos - (pos / 7) * 7;
  const half_t* aBase = in + (size_t)((li * 9 + oy) * 9 + ox) * 64 + sseg * 8;
  const half_t* bBase = w3T + srow * 64 + sseg * 8;
  uint4 aReg = *(const uint4*)aBase;          // s=0: tap0 chunk0
  uint4 bReg = *(const uint4*)bBase;
  f32x4 acc[4];
#pragma unroll
  for (int t = 0; t < 4; ++t) acc[t] = (f32x4){0.f, 0.f, 0.f, 0.f};
#pragma unroll
  for (int s = 0; s < 18; ++s) {
    __syncthreads();
    *(uint4*)&As[srow * 40 + sseg * 8] = aReg;
    *(uint4*)&Bs[srow * 40 + sseg * 8] = bReg;
    __syncthreads();
    if (s < 17) {                             // prefetch next (tap,chunk)
      int ns = s + 1, tap = ns >> 1, ch = ns & 1;
      int ky = tap / 3, kx = tap - ky * 3;
      aReg = *(const uint4*)(aBase + ((ky * 9 + kx) * 64 + ch * 32));
      bReg = *(const uint4*)(bBase + (tap * 4096 + ch * 32));
    }
    half8 af = *(const half8*)&As[(w * 16 + lc) * 40 + q * 8];
#pragma unroll
    for (int t = 0; t < 4; ++t) {
      half8 bf = *(const half8*)&Bs[(t * 16 + lc) * 40 + q * 8];
      acc[t] = __builtin_amdgcn_mfma_f32_16x16x32_f16(af, bf, acc[t], 0, 0, 0);
    }
  }
  // write k-order c*49+pos (fc_mfma consumes this order; wfcT unchanged)
#pragma unroll
  for (int t = 0; t < 4; ++t) {
#pragma unroll
    for (int r = 0; r < 4; ++r) {
      int mr = m0 + w * 16 + q * 4 + r;
      int li2 = mr / 49, pos2 = mr - li2 * 49;
      int col = t * 16 + lc;
      out[(size_t)li2 * 3136 + col * 49 + pos2] =
          (half_t)fmaxf(acc[t][r] + b3[col], 0.f);
    }
  }
}

// ---------------- FC via MFMA: h = relu(A[2048,3136] @ wfc + bfc) -----------
// Unchanged from R6 (proven). A fp16 rows k=c*49+pos, Bt=wfcT fp16 [512][3136].
__global__ __launch_bounds__(256) void fc_mfma(
    const half_t* __restrict__ A, const half_t* __restrict__ Bt,
    const float* __restrict__ bias, float* __restrict__ C) {
  __shared__ __align__(16) half_t As[64 * 40];
  __shared__ __align__(16) half_t Bs[64 * 40];
  int tid = threadIdx.x;
  int m0 = blockIdx.y * 64, n0 = blockIdx.x * 64;
  int w = tid >> 6;
  int l = tid & 63;
  int lc = l & 15, q = l >> 4;
  int srow = tid >> 2, sseg = tid & 3;

  const half_t* aPtr = A + (size_t)(m0 + srow) * 3136 + sseg * 8;
  const half_t* bPtr = Bt + (size_t)(n0 + srow) * 3136 + sseg * 8;
  uint4 aReg = *(const uint4*)aPtr;
  uint4 bReg = *(const uint4*)bPtr;

  f32x4 acc[4];
#pragma unroll
  for (int t = 0; t < 4; ++t) acc[t] = (f32x4){0.f, 0.f, 0.f, 0.f};

  for (int k0 = 0; k0 < 3136; k0 += 32) {
    __syncthreads();
    *(uint4*)&As[srow * 40 + sseg * 8] = aReg;
    *(uint4*)&Bs[srow * 40 + sseg * 8] = bReg;
    __syncthreads();
    if (k0 + 32 < 3136) {                    // prefetch overlaps MFMA below
      aReg = *(const uint4*)(aPtr + k0 + 32);
      bReg = *(const uint4*)(bPtr + k0 + 32);
    }
    half8 af = *(const half8*)&As[(w * 16 + lc) * 40 + q * 8];
#pragma unroll
    for (int t = 0; t < 4; ++t) {
      half8 bf = *(const half8*)&Bs[(t * 16 + lc) * 40 + q * 8];
      acc[t] = __builtin_amdgcn_mfma_f32_16x16x32_f16(af, bf, acc[t], 0, 0, 0);
    }
  }
#pragma unroll
  for (int t = 0; t < 4; ++t) {
#pragma unroll
    for (int r = 0; r < 4; ++r) {
      int row = m0 + w * 16 + q * 4 + r;
      int col = n0 + t * 16 + lc;
      C[(size_t)row * 512 + col] = fmaxf(acc[t][r] + bias[col], 0.f);
    }
  }
}

// ---------------- wfeat = h @ Ww + bw : [2048,512]@[512,32] ----------------
__global__ __launch_bounds__(256) void wfeat_kernel(
    const float* __restrict__ h, const float* __restrict__ Ww,
    const float* __restrict__ bw, float* __restrict__ wf) {
  int g = blockIdx.x * 256 + threadIdx.x;   // 65536
  int row = g >> 5, oc = g & 31;
  float acc = bw[oc];
  const float* hr = h + (size_t)row * 512;
#pragma unroll 8
  for (int k = 0; k < 512; ++k) acc += hr[k] * Ww[k * 32 + oc];
  wf[g] = acc;
}

// ---------------- posfeat: one-hot MLP, one wave per row ----------------
__global__ __launch_bounds__(256) void posfeat_kernel(
    const int* __restrict__ pos, const float* __restrict__ wp1,
    const float* __restrict__ bp1, const float* __restrict__ wp2,
    const float* __restrict__ bp2, float* __restrict__ pf) {
  int row = (blockIdx.x * 256 + threadIdx.x) >> 6;  // 2048
  int l = threadIdx.x & 63;
  int p0 = pos[row * 2], p1 = pos[row * 2 + 1];
  float t1 = fmaxf(wp1[p0 * 64 + l] + wp1[(16 + p1) * 64 + l] + bp1[l], 0.f);
  float acc = bp2[l];
#pragma unroll
  for (int k = 0; k < 64; ++k) acc += __shfl(t1, k) * wp2[k * 64 + l];
  pf[row * 64 + l] = acc;
}

// ---------------- y0 = state0 @ [wpo1|wv1] : [64,8192]@[8192,128] ----------------
__global__ __launch_bounds__(256) void y0_kernel(
    const float* __restrict__ s0, const float* __restrict__ wpo1,
    const float* __restrict__ wv1, float* __restrict__ y0) {
  int g = blockIdx.x * 256 + threadIdx.x;   // 65536: (b, ks, n)
  int n = g & 127, ks = (g >> 7) & 7, b = g >> 10;
  const float* W = (n < 64) ? (wpo1 + n) : (wv1 + (n - 64));
  const float* s = s0 + (size_t)b * 8192 + ks * 1024;
  float acc = 0.f;
#pragma unroll 4
  for (int j = 0; j < 1024; ++j) acc += s[j] * W[(size_t)(ks * 1024 + j) * 64];
  atomicAdd(y0 + b * 128 + n, acc);
}

// ---------------- ystate: recurrence for hidden@W1 (cols 0..8191) ----------------
__global__ __launch_bounds__(128) void ystate_kernel(
    const float* __restrict__ y0, const float* __restrict__ done,
    const int* __restrict__ pos, const float* __restrict__ wf,
    const float* __restrict__ wpo1, const float* __restrict__ wv1,
    float* __restrict__ ys) {
  int b = blockIdx.x;
  int n = threadIdx.x;                      // 0..127
  const float* W = (n < 64) ? (wpo1 + n) : (wv1 + (n - 64));
  float y = y0[b * 128 + n];
  for (int t = 0; t < TT; ++t) {
    int row = t * BB + b;
    float mask = 1.f - done[row];
    int off = pos[row * 2] * 16 + pos[row * 2 + 1];
    y *= mask;
    const float* wfr = wf + row * 32;
#pragma unroll
    for (int c = 0; c < 32; ++c) y += wfr[c] * W[(size_t)(c * 256 + off) * 64];
    ys[(size_t)row * 128 + n] = y;
  }
}

// ---------------- final map state (output 2) ----------------
__global__ __launch_bounds__(256) void state_kernel(
    const float* __restrict__ s0, const float* __restrict__ done,
    const int* __restrict__ pos, const float* __restrict__ wf,
    float* __restrict__ out_state) {
  int b = blockIdx.x, tid = threadIdx.x;    // tid = spatial offset 0..255
  float s[32];
#pragma unroll
  for (int c = 0; c < 32; ++c) s[c] = s0[(size_t)b * 8192 + c * 256 + tid];
  for (int t = 0; t < TT; ++t) {
    int row = t * BB + b;
    float mask = 1.f - done[row];
    int off = pos[row * 2] * 16 + pos[row * 2 + 1];
#pragma unroll
    for (int c = 0; c < 32; ++c) s[c] *= mask;
    if (tid == off) {
#pragma unroll
      for (int c = 0; c < 32; ++c) s[c] += wf[row * 32 + c];
    }
  }
#pragma unroll
  for (int c = 0; c < 32; ++c) out_state[(size_t)b * 8192 + c * 256 + tid] = s[c];
}

// ---------------- heads: + pos-part of W1, ReLU, second layers ----------------
__global__ __launch_bounds__(256) void head_kernel(
    const float* __restrict__ ys, const float* __restrict__ pf,
    const float* __restrict__ wpo1, const float* __restrict__ wv1,
    const float* __restrict__ bpo1, const float* __restrict__ bv1,
    const float* __restrict__ wpo2, const float* __restrict__ bpo2,
    const float* __restrict__ wv2, const float* __restrict__ bv2,
    float* __restrict__ logits, float* __restrict__ vout) {
  int row = (blockIdx.x * 256 + threadIdx.x) >> 6;  // one wave per row
  int l = threadIdx.x & 63;
  float pfv = pf[row * 64 + l];
  float accp = bpo1[l] + ys[(size_t)row * 128 + l];
  float accv = bv1[l] + ys[(size_t)row * 128 + 64 + l];
#pragma unroll
  for (int k = 0; k < 64; ++k) {
    float pk = __shfl(pfv, k);
    accp += pk * wpo1[(size_t)(8192 + k) * 64 + l];
    accv += pk * wv1[(size_t)(8192 + k) * 64 + l];
  }
  float rp = fmaxf(accp, 0.f), rv = fmaxf(accv, 0.f);
#pragma unroll
  for (int a = 0; a < 5; ++a) {
    float pa = rp * wpo2[l * 5 + a];
#pragma unroll
    for (int m = 32; m >= 1; m >>= 1) pa += __shfl_xor(pa, m);
    if (l == 0) logits[row * 5 + a] = pa + bpo2[a];
  }
  float pv = rv * wv2[l];
#pragma unroll
  for (int m = 32; m >= 1; m >>= 1) pv += __shfl_xor(pv, m);
  if (l == 0) vout[row] = pv + bv2[0];
}

extern "C" void kernel_launch(void* const* d_in, const int* in_sizes, int n_in,
                              void* d_out, int out_size, void* d_ws, size_t ws_size,
                              hipStream_t stream) {
  const float* image = (const float*)d_in[0];
  const float* done = (const float*)d_in[1];
  const float* state0 = (const float*)d_in[2];
  const int* position = (const int*)d_in[3];
  const float* w1 = (const float*)d_in[4];
  const float* b1 = (const float*)d_in[5];
  const float* w2 = (const float*)d_in[6];
  const float* b2 = (const float*)d_in[7];
  const float* w3 = (const float*)d_in[8];
  const float* b3 = (const float*)d_in[9];
  const float* wfc = (const float*)d_in[10];
  const float* bfc = (const float*)d_in[11];
  const float* Ww = (const float*)d_in[12];
  const float* bw = (const float*)d_in[13];
  const float* wp1 = (const float*)d_in[14];
  const float* bp1 = (const float*)d_in[15];
  const float* wp2 = (const float*)d_in[16];
  const float* bp2 = (const float*)d_in[17];
  const float* wpo1 = (const float*)d_in[18];
  const float* bpo1 = (const float*)d_in[19];
  const float* wpo2 = (const float*)d_in[20];
  const float* bpo2 = (const float*)d_in[21];
  const float* wv1 = (const float*)d_in[22];
  const float* bv1 = (const float*)d_in[23];
  const float* wv2 = (const float*)d_in[24];
  const float* bv2 = (const float*)d_in[25];

  float* ws = (float*)d_ws;
  float* w1t = ws + OFF_W1T;
  half_t* w2T = (half_t*)(ws + OFF_W2T);
  half_t* w3T = (half_t*)(ws + OFF_W3T);
  float* wf = ws + OFF_WF;
  float* pfb = ws + OFF_PF;
  float* y0 = ws + OFF_Y0;
  float* ysb = ws + OFF_YS;
  float* h = ws + OFF_H;
  half_t* wfcT = (half_t*)(ws + OFF_WFCT);
  half_t* c3b = (half_t*)(ws + OFF_C3);
  half_t* c2b = (half_t*)(ws + OFF_C2);
  half_t* c1b = (half_t*)(ws + OFF_C1);

  float* out = (float*)d_out;
  float* out_logits = out;            // [2048,5]
  float* out_v = out + 10240;         // [2048,1]
  float* out_state = out + 12288;     // [64,32,16,16]

  // Tier by ws_size (floats): A: CS=2048 no chunk, 95.9 MB;
  //                           B: CS=1024, 69.7 MB; C: CS=512, 56.6 MB.
  int CS;
  if (ws_size >= (size_t)23986176 * 4) CS = 2048;
  else if (ws_size >= (size_t)17432576 * 4) CS = 1024;
  else CS = 512;
  int nc = TBR / CS;

  hipMemsetAsync(y0, 0, 8192 * sizeof(float), stream);
  prep_kernel<<<296, 256, 0, stream>>>(w1, w2, w3, w1t, w2T, w3T);
  prep_wfct<<<dim3(98, 16), 256, 0, stream>>>(wfc, wfcT);

  for (int c = 0; c < nc; ++c) {
    int n0 = c * CS;
    conv1_kernel<<<CS * 400 / 256, 256, 0, stream>>>(image, w1t, b1, c1b, n0);
    conv2_mfma<<<CS * 81 / 64, 256, 0, stream>>>(
        c1b, w2T, b2, c2b + (size_t)n0 * 5184);
  }
  conv3_mfma<<<TBR * 49 / 64, 256, 0, stream>>>(c2b, w3T, b3, c3b);
  fc_mfma<<<dim3(8, 32), 256, 0, stream>>>(c3b, wfcT, bfc, h);
  wfeat_kernel<<<256, 256, 0, stream>>>(h, Ww, bw, wf);
  posfeat_kernel<<<512, 256, 0, stream>>>(position, wp1, bp1, wp2, bp2, pfb);
  y0_kernel<<<256, 256, 0, stream>>>(state0, wpo1, wv1, y0);
  ystate_kernel<<<64, 128, 0, stream>>>(y0, done, position, wf, wpo1, wv1, ysb);
  state_kernel<<<64, 256, 0, stream>>>(state0, done, position, wf, out_state);
  head_kernel<<<512, 256, 0, stream>>>(ysb, pfb, wpo1, wv1, bpo1, bv1,
                                       wpo2, bpo2, wv2, bv2, out_logits, out_v);
}